// Round 2
// baseline (12865.646 us; speedup 1.0000x reference)
//
#include <hip/hip_runtime.h>
#include <math.h>
#include <stddef.h>

#define B_  4
#define T_  10
#define C_  96
#define H_  32
#define W_  32
#define HW_ 1024
#define L_  13
#define OUT_ 96

__device__ __forceinline__ float leaky_f(float v) { return v >= 0.f ? v : 0.2f * v; }
__device__ __forceinline__ float sigmoid_f(float v) { return 1.f / (1.f + expf(-v)); }

// ---------------------------------------------------------------------------
// 3x3 conv, pad 1, Cin=96 -> Cout=288, input x (B,T,C,H,W) at time t.
// block 256 = 8 rows x 32 cols; grid (4 row-tiles, 36 oc-chunks of 8, B)
// ---------------------------------------------------------------------------
__global__ __launch_bounds__(256) void conv3x3_i2h_k(
    const float* __restrict__ x, const float* __restrict__ w,
    const float* __restrict__ bias, float* __restrict__ out, int t)
{
    const int tx  = threadIdx.x & 31;
    const int ty  = threadIdx.x >> 5;
    const int y0  = blockIdx.x * 8;
    const int oc0 = blockIdx.y * 8;
    const int b   = blockIdx.z;
    const float* xin = x + ((size_t)(b * T_ + t) * C_) * HW_;

    __shared__ float tile[10][34];
    float acc[8] = {0.f,0.f,0.f,0.f,0.f,0.f,0.f,0.f};

    for (int c = 0; c < C_; ++c) {
        const float* xc = xin + (size_t)c * HW_;
        for (int i = threadIdx.x; i < 10 * 34; i += 256) {
            int r = i / 34, cc = i - r * 34;
            int yy = y0 + r - 1, xx = cc - 1;
            tile[r][cc] = (yy >= 0 && yy < 32 && xx >= 0 && xx < 32) ? xc[yy * 32 + xx] : 0.f;
        }
        __syncthreads();
        float v[3][3];
        #pragma unroll
        for (int dy = 0; dy < 3; ++dy)
            #pragma unroll
            for (int dx = 0; dx < 3; ++dx)
                v[dy][dx] = tile[ty + dy][tx + dx];
        const float* wc = w + (size_t)(oc0 * C_ + c) * 9;
        #pragma unroll
        for (int j = 0; j < 8; ++j) {
            const float* wj = wc + (size_t)j * C_ * 9;
            #pragma unroll
            for (int dy = 0; dy < 3; ++dy)
                #pragma unroll
                for (int dx = 0; dx < 3; ++dx)
                    acc[j] = fmaf(v[dy][dx], wj[dy * 3 + dx], acc[j]);
        }
        __syncthreads();
    }
    const int hw = (y0 + ty) * 32 + tx;
    #pragma unroll
    for (int j = 0; j < 8; ++j)
        out[((size_t)b * 288 + oc0 + j) * HW_ + hw] = acc[j] + bias[oc0 + j];
}

// ---------------------------------------------------------------------------
// generic 5x5 conv, pad 2. channel address = (b*in_bstr + c)*HW.
// optional elementwise add (same layout as out) and leaky activation.
// block 256 = 8x32; grid (4, ceil(cout/8), B)
// ---------------------------------------------------------------------------
__global__ __launch_bounds__(256) void conv5x5_k(
    const float* __restrict__ in, int in_bstr, int cin, int cout,
    const float* __restrict__ w, const float* __restrict__ bias,
    const float* __restrict__ addsrc, int do_leaky,
    float* __restrict__ out)
{
    const int tx  = threadIdx.x & 31;
    const int ty  = threadIdx.x >> 5;
    const int y0  = blockIdx.x * 8;
    const int oc0 = blockIdx.y * 8;
    const int b   = blockIdx.z;

    __shared__ float tile[12][36];
    float acc[8] = {0.f,0.f,0.f,0.f,0.f,0.f,0.f,0.f};

    for (int c = 0; c < cin; ++c) {
        const float* xc = in + ((size_t)b * in_bstr + c) * HW_;
        for (int i = threadIdx.x; i < 12 * 36; i += 256) {
            int r = i / 36, cc = i - r * 36;
            int yy = y0 + r - 2, xx = cc - 2;
            tile[r][cc] = (yy >= 0 && yy < 32 && xx >= 0 && xx < 32) ? xc[yy * 32 + xx] : 0.f;
        }
        __syncthreads();
        float v[5][5];
        #pragma unroll
        for (int dy = 0; dy < 5; ++dy)
            #pragma unroll
            for (int dx = 0; dx < 5; ++dx)
                v[dy][dx] = tile[ty + dy][tx + dx];
        #pragma unroll
        for (int j = 0; j < 8; ++j) {
            if (oc0 + j < cout) {
                const float* wj = w + ((size_t)(oc0 + j) * cin + c) * 25;
                #pragma unroll
                for (int dy = 0; dy < 5; ++dy)
                    #pragma unroll
                    for (int dx = 0; dx < 5; ++dx)
                        acc[j] = fmaf(v[dy][dx], wj[dy * 5 + dx], acc[j]);
            }
        }
        __syncthreads();
    }
    const int hw = (y0 + ty) * 32 + tx;
    #pragma unroll
    for (int j = 0; j < 8; ++j) {
        int oc = oc0 + j;
        if (oc < cout) {
            float r = acc[j] + bias[oc];
            if (addsrc) r += addsrc[((size_t)b * cout + oc) * HW_ + hw];
            if (do_leaky) r = leaky_f(r);
            out[((size_t)b * cout + oc) * HW_ + hw] = r;
        }
    }
}

// ---------------------------------------------------------------------------
// bilinear warp: warped[b, l*C+c, hw] = sample(h[b,c], grid - flow), zero pad
// grid (4, L, B); block 256; one pixel per thread, loop over C.
// ---------------------------------------------------------------------------
__global__ __launch_bounds__(256) void warp_k(
    const float* __restrict__ h, const float* __restrict__ flows,
    float* __restrict__ warped)
{
    const int hw = blockIdx.x * 256 + threadIdx.x;
    const int l  = blockIdx.y;
    const int b  = blockIdx.z;
    const int py = hw >> 5, px = hw & 31;

    const float fx = flows[((size_t)b * (2 * L_) + 2 * l) * HW_ + hw];
    const float fy = flows[((size_t)b * (2 * L_) + 2 * l + 1) * HW_ + hw];
    const float gx = (float)px - fx;
    const float gy = (float)py - fy;
    const float x0f = floorf(gx), y0f = floorf(gy);
    const float wx = gx - x0f, wy = gy - y0f;
    const int x0 = (int)x0f, y0 = (int)y0f;
    const int x1 = x0 + 1, y1 = y0 + 1;

    const bool vx0 = (x0 >= 0 && x0 <= 31), vx1 = (x1 >= 0 && x1 <= 31);
    const bool vy0 = (y0 >= 0 && y0 <= 31), vy1 = (y1 >= 0 && y1 <= 31);
    const int xc0 = min(max(x0, 0), 31), xc1 = min(max(x1, 0), 31);
    const int yc0 = min(max(y0, 0), 31), yc1 = min(max(y1, 0), 31);
    const int o00 = yc0 * 32 + xc0, o01 = yc0 * 32 + xc1;
    const int o10 = yc1 * 32 + xc0, o11 = yc1 * 32 + xc1;
    const float w00 = (vx0 && vy0) ? (1.f - wx) * (1.f - wy) : 0.f;
    const float w01 = (vx1 && vy0) ? wx * (1.f - wy) : 0.f;
    const float w10 = (vx0 && vy1) ? (1.f - wx) * wy : 0.f;
    const float w11 = (vx1 && vy1) ? wx * wy : 0.f;

    const float* hb = h + (size_t)b * C_ * HW_;
    float* ob = warped + ((size_t)b * (L_ * C_) + (size_t)l * C_) * HW_ + hw;
    for (int c = 0; c < C_; ++c) {
        const float* hc = hb + (size_t)c * HW_;
        float r = hc[o00] * w00 + hc[o01] * w01 + hc[o10] * w10 + hc[o11] * w11;
        ob[(size_t)c * HW_] = r;
    }
}

// ---------------------------------------------------------------------------
// 1x1 "ret" conv = GEMM: h2h[b,oc,hw] = sum_k ret_w[oc,k] * warped[b,k,hw] + b
// grid (4, 36, B); block 256; 1 pixel x 8 oc per thread; K staged 8-wide in LDS
// ---------------------------------------------------------------------------
__global__ __launch_bounds__(256) void ret1x1_k(
    const float* __restrict__ warped, const float* __restrict__ w,
    const float* __restrict__ bias, float* __restrict__ out)
{
    const int pix0 = blockIdx.x * 256;
    const int oc0  = blockIdx.y * 8;
    const int b    = blockIdx.z;
    const int K = L_ * C_;  // 1248

    __shared__ float sk[8][256];
    float acc[8] = {0.f,0.f,0.f,0.f,0.f,0.f,0.f,0.f};
    const float* wb = warped + (size_t)b * K * HW_ + pix0;

    for (int k0 = 0; k0 < K; k0 += 8) {
        #pragma unroll
        for (int kk = 0; kk < 8; ++kk)
            sk[kk][threadIdx.x] = wb[(size_t)(k0 + kk) * HW_ + threadIdx.x];
        __syncthreads();
        #pragma unroll
        for (int kk = 0; kk < 8; ++kk) {
            float v = sk[kk][threadIdx.x];
            const int k = k0 + kk;
            #pragma unroll
            for (int j = 0; j < 8; ++j)
                acc[j] = fmaf(v, w[(size_t)(oc0 + j) * K + k], acc[j]);
        }
        __syncthreads();
    }
    const int hw = pix0 + threadIdx.x;
    #pragma unroll
    for (int j = 0; j < 8; ++j)
        out[((size_t)b * 288 + oc0 + j) * HW_ + hw] = acc[j] + bias[oc0 + j];
}

// ---------------------------------------------------------------------------
// GRU gate update. Also writes h_next into ys at channel slot t*C+c.
// ---------------------------------------------------------------------------
__global__ __launch_bounds__(256) void gru_k(
    const float* __restrict__ i2h_t, const float* __restrict__ h2h,
    const float* __restrict__ h, float* __restrict__ h_next,
    float* __restrict__ ys, int t)
{
    const int idx = blockIdx.x * 256 + threadIdx.x;  // over B*C*HW
    if (idx >= B_ * C_ * HW_) return;
    const int hw = idx & (HW_ - 1);
    const int c  = (idx >> 10) % C_;
    const int b  = idx / (C_ * HW_);
    const size_t base = (size_t)b * 288 * HW_;

    const float ir = i2h_t[base + (size_t)c * HW_ + hw];
    const float iu = i2h_t[base + (size_t)(96 + c) * HW_ + hw];
    const float im = i2h_t[base + (size_t)(192 + c) * HW_ + hw];
    const float hr = h2h[base + (size_t)c * HW_ + hw];
    const float hu = h2h[base + (size_t)(96 + c) * HW_ + hw];
    const float hm = h2h[base + (size_t)(192 + c) * HW_ + hw];

    const float r = sigmoid_f(ir + hr);
    const float u = sigmoid_f(iu + hu);
    const float mem = leaky_f(im + r * hm);
    const float hv = h[idx];
    const float hn = u * hv + (1.f - u) * mem;
    h_next[idx] = hn;
    ys[((size_t)b * (T_ * C_) + (size_t)t * C_ + c) * HW_ + hw] = hn;
}

// ---------------------------------------------------------------------------
// ConvTranspose2d k=4 s=2 p=1, 960 -> 960, 32x32 -> 64x64, + bias + leaky.
// ct_w layout (in, out, kh, kw). Each thread computes the 2x2 output quad of
// one input-space position for 8 output channels; all 16 taps used ->
// wave-uniform weight loads. block 256 = 32x8 input-space; grid (4, 120, B).
// out[oy,ox] += in[iy,ix] * w[ic,oc,ky,kx] with oy = 2*iy - 1 + ky.
// For quad (2y+ry, 2x+rx): iy = y-1+a+ry, ky = 3-2a-ry (a in {0,1}).
// ---------------------------------------------------------------------------
__global__ __launch_bounds__(256) void convtrans_k(
    const float* __restrict__ y, const float* __restrict__ w,
    const float* __restrict__ bias, float* __restrict__ out)
{
    const int tx  = threadIdx.x & 31;   // input-space x 0..31
    const int ty  = threadIdx.x >> 5;   // 0..7
    const int iy0 = blockIdx.x * 8;
    const int oc0 = blockIdx.y * 8;
    const int b   = blockIdx.z;
    const int NC = T_ * C_;  // 960

    __shared__ float tile[10][34];
    float acc[8][2][2];
    #pragma unroll
    for (int j = 0; j < 8; ++j)
        #pragma unroll
        for (int ry = 0; ry < 2; ++ry)
            #pragma unroll
            for (int rx = 0; rx < 2; ++rx) acc[j][ry][rx] = 0.f;

    const float* yb = y + (size_t)b * NC * HW_;
    for (int ic = 0; ic < NC; ++ic) {
        const float* yc = yb + (size_t)ic * HW_;
        for (int i = threadIdx.x; i < 10 * 34; i += 256) {
            int r = i / 34, cc = i - r * 34;
            int yy = iy0 + r - 1, xx = cc - 1;
            tile[r][cc] = (yy >= 0 && yy < 32 && xx >= 0 && xx < 32) ? yc[yy * 32 + xx] : 0.f;
        }
        __syncthreads();
        float v[3][3];
        #pragma unroll
        for (int dy = 0; dy < 3; ++dy)
            #pragma unroll
            for (int dx = 0; dx < 3; ++dx)
                v[dy][dx] = tile[ty + dy][tx + dx];
        const float* wc = w + ((size_t)ic * NC + oc0) * 16;
        #pragma unroll
        for (int j = 0; j < 8; ++j) {
            const float* wj = wc + (size_t)j * 16;
            #pragma unroll
            for (int ry = 0; ry < 2; ++ry)
                #pragma unroll
                for (int rx = 0; rx < 2; ++rx)
                    #pragma unroll
                    for (int a = 0; a < 2; ++a)
                        #pragma unroll
                        for (int e = 0; e < 2; ++e)
                            acc[j][ry][rx] = fmaf(v[a + ry][e + rx],
                                                  wj[(3 - 2*a - ry) * 4 + (3 - 2*e - rx)],
                                                  acc[j][ry][rx]);
        }
        __syncthreads();
    }
    const int oyb = 2 * (iy0 + ty);
    #pragma unroll
    for (int j = 0; j < 8; ++j) {
        const float bs = bias[oc0 + j];
        #pragma unroll
        for (int ry = 0; ry < 2; ++ry) {
            float a0 = leaky_f(acc[j][ry][0] + bs);
            float a1 = leaky_f(acc[j][ry][1] + bs);
            float2 pr; pr.x = a0; pr.y = a1;
            *reinterpret_cast<float2*>(out + (((size_t)b * NC + oc0 + j) * 64 + oyb + ry) * 64 + 2 * tx) = pr;
        }
    }
}

// ---------------------------------------------------------------------------
extern "C" void kernel_launch(void* const* d_in, const int* in_sizes, int n_in,
                              void* d_out, int out_size, void* d_ws, size_t ws_size,
                              hipStream_t stream)
{
    const float* x      = (const float*)d_in[0];
    const float* h0     = (const float*)d_in[1];
    const float* i2h_w  = (const float*)d_in[2];
    const float* i2h_b  = (const float*)d_in[3];
    const float* i2f_w  = (const float*)d_in[4];
    const float* i2f_b  = (const float*)d_in[5];
    const float* h2f_w  = (const float*)d_in[6];
    const float* h2f_b  = (const float*)d_in[7];
    const float* flow_w = (const float*)d_in[8];
    const float* flow_b = (const float*)d_in[9];
    const float* ret_w  = (const float*)d_in[10];
    const float* ret_b  = (const float*)d_in[11];
    const float* ct_w   = (const float*)d_in[12];
    const float* ct_b   = (const float*)d_in[13];
    float* out = (float*)d_out;

    char* p = (char*)d_ws;
    float* i2h_t  = (float*)p; p += (size_t)B_ * 288 * HW_ * 4;           // 4.72 MB
    float* i2f_t  = (float*)p; p += (size_t)B_ * 32 * HW_ * 4;            // 0.52 MB
    float* f_buf  = (float*)p; p += (size_t)B_ * 32 * HW_ * 4;            // 0.52 MB
    float* flows  = (float*)p; p += (size_t)B_ * 26 * HW_ * 4;            // 0.43 MB
    float* warped = (float*)p; p += (size_t)B_ * (L_ * C_) * HW_ * 4;     // 20.45 MB
    float* h2h    = (float*)p; p += (size_t)B_ * 288 * HW_ * 4;           // 4.72 MB
    float* hA     = (float*)p; p += (size_t)B_ * C_ * HW_ * 4;            // 1.57 MB
    float* hB     = (float*)p; p += (size_t)B_ * C_ * HW_ * 4;            // 1.57 MB
    float* ys     = (float*)p; p += (size_t)B_ * (T_ * C_) * HW_ * 4;     // 15.73 MB

    const float* h_cur = h0;
    float* hbuf[2] = {hA, hB};

    for (int t = 0; t < T_; ++t) {
        conv3x3_i2h_k<<<dim3(4, 36, B_), 256, 0, stream>>>(x, i2h_w, i2h_b, i2h_t, t);
        conv5x5_k<<<dim3(4, 4, B_), 256, 0, stream>>>(
            x + (size_t)t * C_ * HW_, T_ * C_, C_, 32, i2f_w, i2f_b, nullptr, 0, i2f_t);
        conv5x5_k<<<dim3(4, 4, B_), 256, 0, stream>>>(
            h_cur, C_, C_, 32, h2f_w, h2f_b, i2f_t, 1, f_buf);
        conv5x5_k<<<dim3(4, 4, B_), 256, 0, stream>>>(
            f_buf, 32, 32, 2 * L_, flow_w, flow_b, nullptr, 0, flows);
        warp_k<<<dim3(4, L_, B_), 256, 0, stream>>>(h_cur, flows, warped);
        ret1x1_k<<<dim3(4, 36, B_), 256, 0, stream>>>(warped, ret_w, ret_b, h2h);
        float* h_next = hbuf[t & 1];
        gru_k<<<dim3((B_ * C_ * HW_) / 256), 256, 0, stream>>>(i2h_t, h2h, h_cur, h_next, ys, t);
        h_cur = h_next;
    }
    convtrans_k<<<dim3(4, 120, B_), 256, 0, stream>>>(ys, ct_w, ct_b, out);
}

// Round 3
// 9320.616 us; speedup vs baseline: 1.3803x; 1.3803x over previous
//
#include <hip/hip_runtime.h>
#include <math.h>
#include <stddef.h>

#define B_  4
#define T_  10
#define C_  96
#define H_  32
#define W_  32
#define HW_ 1024
#define L_  13
#define OUT_ 96

__device__ __forceinline__ float leaky_f(float v) { return v >= 0.f ? v : 0.2f * v; }
__device__ __forceinline__ float sigmoid_f(float v) { return 1.f / (1.f + expf(-v)); }

// ---------------------------------------------------------------------------
// 3x3 conv, pad 1, Cin=96 -> Cout=288, ALL timesteps at once.
// x (B,T,C,H,W); out (T,B,288,HW). grid (4 row-tiles, 36 oc-chunks, T*B)
// ---------------------------------------------------------------------------
__global__ __launch_bounds__(256) void conv3x3_i2h_k(
    const float* __restrict__ x, const float* __restrict__ w,
    const float* __restrict__ bias, float* __restrict__ out)
{
    const int tx  = threadIdx.x & 31;
    const int ty  = threadIdx.x >> 5;
    const int y0  = blockIdx.x * 8;
    const int oc0 = blockIdx.y * 8;
    const int n   = blockIdx.z;          // t*B + b
    const int b   = n % B_;
    const int t   = n / B_;
    const float* xin = x + ((size_t)(b * T_ + t) * C_) * HW_;

    __shared__ float tile[10][34];
    float acc[8] = {0.f,0.f,0.f,0.f,0.f,0.f,0.f,0.f};

    for (int c = 0; c < C_; ++c) {
        const float* xc = xin + (size_t)c * HW_;
        for (int i = threadIdx.x; i < 10 * 34; i += 256) {
            int r = i / 34, cc = i - r * 34;
            int yy = y0 + r - 1, xx = cc - 1;
            tile[r][cc] = (yy >= 0 && yy < 32 && xx >= 0 && xx < 32) ? xc[yy * 32 + xx] : 0.f;
        }
        __syncthreads();
        float v[3][3];
        #pragma unroll
        for (int dy = 0; dy < 3; ++dy)
            #pragma unroll
            for (int dx = 0; dx < 3; ++dx)
                v[dy][dx] = tile[ty + dy][tx + dx];
        const float* wc = w + (size_t)(oc0 * C_ + c) * 9;
        #pragma unroll
        for (int j = 0; j < 8; ++j) {
            const float* wj = wc + (size_t)j * C_ * 9;
            #pragma unroll
            for (int dy = 0; dy < 3; ++dy)
                #pragma unroll
                for (int dx = 0; dx < 3; ++dx)
                    acc[j] = fmaf(v[dy][dx], wj[dy * 3 + dx], acc[j]);
        }
        __syncthreads();
    }
    const int hw = (y0 + ty) * 32 + tx;
    #pragma unroll
    for (int j = 0; j < 8; ++j)
        out[((size_t)n * 288 + oc0 + j) * HW_ + hw] = acc[j] + bias[oc0 + j];
}

// ---------------------------------------------------------------------------
// 5x5 conv, pad 2, hoisted over T: x (B,T,C,HW) -> out (T,B,32,HW).
// block 256 = (2 rows x 32 cols) x 4 oc-pairs; grid (16, 4, T*B)
// ---------------------------------------------------------------------------
__global__ __launch_bounds__(256) void conv5x5_x_k(
    const float* __restrict__ x, const float* __restrict__ w,
    const float* __restrict__ bias, float* __restrict__ out)
{
    const int px  = threadIdx.x & 63;
    const int g   = threadIdx.x >> 6;
    const int row = px >> 5, col = px & 31;
    const int y0  = blockIdx.x * 2;
    const int oc0 = blockIdx.y * 8 + g * 2;
    const int n   = blockIdx.z;
    const int b   = n % B_;
    const int t   = n / B_;
    const float* xin = x + ((size_t)(b * T_ + t) * C_) * HW_;

    __shared__ float tile[6][36];
    float acc0 = 0.f, acc1 = 0.f;

    for (int c = 0; c < C_; ++c) {
        const float* xc = xin + (size_t)c * HW_;
        if (threadIdx.x < 216) {
            int r = threadIdx.x / 36, cc = threadIdx.x % 36;
            int yy = y0 + r - 2, xx = cc - 2;
            tile[r][cc] = (yy >= 0 && yy < 32 && xx >= 0 && xx < 32) ? xc[yy * 32 + xx] : 0.f;
        }
        __syncthreads();
        const float* w0 = w + ((size_t)oc0 * C_ + c) * 25;
        const float* w1 = w0 + (size_t)C_ * 25;
        #pragma unroll
        for (int dy = 0; dy < 5; ++dy)
            #pragma unroll
            for (int dx = 0; dx < 5; ++dx) {
                float v = tile[row + dy][col + dx];
                acc0 = fmaf(v, w0[dy * 5 + dx], acc0);
                acc1 = fmaf(v, w1[dy * 5 + dx], acc1);
            }
        __syncthreads();
    }
    const int hw = (y0 + row) * 32 + col;
    out[((size_t)n * 32 + oc0) * HW_ + hw]     = acc0 + bias[oc0];
    out[((size_t)n * 32 + oc0 + 1) * HW_ + hw] = acc1 + bias[oc0 + 1];
}

// ---------------------------------------------------------------------------
// per-step generic 5x5 conv, pad 2. in channel at (b*in_bstr + c)*HW.
// optional add (layout (B,cout,HW)) + leaky. block 256 = 64px x 4 oc-pairs;
// grid (16, ceil(cout/8), B)
// ---------------------------------------------------------------------------
__global__ __launch_bounds__(256) void conv5x5_k(
    const float* __restrict__ in, int in_bstr, int cin, int cout,
    const float* __restrict__ w, const float* __restrict__ bias,
    const float* __restrict__ addsrc, int do_leaky,
    float* __restrict__ out)
{
    const int px  = threadIdx.x & 63;
    const int g   = threadIdx.x >> 6;
    const int row = px >> 5, col = px & 31;
    const int y0  = blockIdx.x * 2;
    const int oc0 = blockIdx.y * 8 + g * 2;
    const int b   = blockIdx.z;
    // clamp weight row so inactive oc never reads OOB
    const int ocw0 = min(oc0, cout - 1);
    const int ocw1 = min(oc0 + 1, cout - 1);

    __shared__ float tile[6][36];
    float acc0 = 0.f, acc1 = 0.f;

    for (int c = 0; c < cin; ++c) {
        const float* xc = in + ((size_t)b * in_bstr + c) * HW_;
        if (threadIdx.x < 216) {
            int r = threadIdx.x / 36, cc = threadIdx.x % 36;
            int yy = y0 + r - 2, xx = cc - 2;
            tile[r][cc] = (yy >= 0 && yy < 32 && xx >= 0 && xx < 32) ? xc[yy * 32 + xx] : 0.f;
        }
        __syncthreads();
        const float* w0 = w + ((size_t)ocw0 * cin + c) * 25;
        const float* w1 = w + ((size_t)ocw1 * cin + c) * 25;
        #pragma unroll
        for (int dy = 0; dy < 5; ++dy)
            #pragma unroll
            for (int dx = 0; dx < 5; ++dx) {
                float v = tile[row + dy][col + dx];
                acc0 = fmaf(v, w0[dy * 5 + dx], acc0);
                acc1 = fmaf(v, w1[dy * 5 + dx], acc1);
            }
        __syncthreads();
    }
    const int hw = (y0 + row) * 32 + col;
    if (oc0 < cout) {
        float r = acc0 + bias[oc0];
        if (addsrc) r += addsrc[((size_t)b * cout + oc0) * HW_ + hw];
        if (do_leaky) r = leaky_f(r);
        out[((size_t)b * cout + oc0) * HW_ + hw] = r;
    }
    if (oc0 + 1 < cout) {
        float r = acc1 + bias[oc0 + 1];
        if (addsrc) r += addsrc[((size_t)b * cout + oc0 + 1) * HW_ + hw];
        if (do_leaky) r = leaky_f(r);
        out[((size_t)b * cout + oc0 + 1) * HW_ + hw] = r;
    }
}

// ---------------------------------------------------------------------------
// bilinear warp. block 256 = 64 px x 4 channel-groups (24 ch each);
// grid (16, L, B)
// ---------------------------------------------------------------------------
__global__ __launch_bounds__(256) void warp_k(
    const float* __restrict__ h, const float* __restrict__ flows,
    float* __restrict__ warped)
{
    const int hw = (blockIdx.x << 6) + (threadIdx.x & 63);
    const int cg = threadIdx.x >> 6;  // 0..3
    const int l  = blockIdx.y;
    const int b  = blockIdx.z;
    const int py = hw >> 5, px = hw & 31;

    const float fx = flows[((size_t)b * (2 * L_) + 2 * l) * HW_ + hw];
    const float fy = flows[((size_t)b * (2 * L_) + 2 * l + 1) * HW_ + hw];
    const float gx = (float)px - fx;
    const float gy = (float)py - fy;
    const float x0f = floorf(gx), y0f = floorf(gy);
    const float wx = gx - x0f, wy = gy - y0f;
    const int x0 = (int)x0f, y0 = (int)y0f;
    const int x1 = x0 + 1, y1 = y0 + 1;

    const bool vx0 = (x0 >= 0 && x0 <= 31), vx1 = (x1 >= 0 && x1 <= 31);
    const bool vy0 = (y0 >= 0 && y0 <= 31), vy1 = (y1 >= 0 && y1 <= 31);
    const int xc0 = min(max(x0, 0), 31), xc1 = min(max(x1, 0), 31);
    const int yc0 = min(max(y0, 0), 31), yc1 = min(max(y1, 0), 31);
    const int o00 = yc0 * 32 + xc0, o01 = yc0 * 32 + xc1;
    const int o10 = yc1 * 32 + xc0, o11 = yc1 * 32 + xc1;
    const float w00 = (vx0 && vy0) ? (1.f - wx) * (1.f - wy) : 0.f;
    const float w01 = (vx1 && vy0) ? wx * (1.f - wy) : 0.f;
    const float w10 = (vx0 && vy1) ? (1.f - wx) * wy : 0.f;
    const float w11 = (vx1 && vy1) ? wx * wy : 0.f;

    const float* hb = h + ((size_t)b * C_ + cg * 24) * HW_;
    float* ob = warped + (((size_t)b * L_ + l) * C_ + cg * 24) * HW_ + hw;
    for (int cc = 0; cc < 24; ++cc) {
        const float* hc = hb + (size_t)cc * HW_;
        ob[(size_t)cc * HW_] = hc[o00] * w00 + hc[o01] * w01 + hc[o10] * w10 + hc[o11] * w11;
    }
}

// ---------------------------------------------------------------------------
// fused ret(1x1 conv) + GRU. Each block: 64 pixels, 8 c-values -> computes
// gate rows {c, 96+c, 192+c} of h2h by streaming K=1248, then applies GRU.
// No LDS, register double-buffered loads. grid (16, 12, B), block 64.
// ---------------------------------------------------------------------------
__global__ __launch_bounds__(64) void retgru_k(
    const float* __restrict__ warped, const float* __restrict__ w,
    const float* __restrict__ bias, const float* __restrict__ i2h_t,
    const float* __restrict__ h, float* __restrict__ h_next,
    float* __restrict__ ys, int t)
{
    const int tid  = threadIdx.x;           // 0..63
    const int hw   = (blockIdx.x << 6) + tid;
    const int c0   = blockIdx.y * 8;
    const int b    = blockIdx.z;
    const int K    = L_ * C_;               // 1248

    const float* wb = warped + (size_t)b * K * HW_ + hw;
    float accR[8] = {0,0,0,0,0,0,0,0};
    float accU[8] = {0,0,0,0,0,0,0,0};
    float accM[8] = {0,0,0,0,0,0,0,0};

    float vcur[8];
    #pragma unroll
    for (int kk = 0; kk < 8; ++kk) vcur[kk] = wb[(size_t)kk * HW_];

    for (int k0 = 0; k0 < K; k0 += 8) {
        float vnxt[8];
        if (k0 + 8 < K) {
            #pragma unroll
            for (int kk = 0; kk < 8; ++kk) vnxt[kk] = wb[(size_t)(k0 + 8 + kk) * HW_];
        } else {
            #pragma unroll
            for (int kk = 0; kk < 8; ++kk) vnxt[kk] = 0.f;
        }
        #pragma unroll
        for (int j = 0; j < 8; ++j) {
            const float* wr = w + (size_t)(c0 + j) * K + k0;
            const float* wu = w + (size_t)(96 + c0 + j) * K + k0;
            const float* wm = w + (size_t)(192 + c0 + j) * K + k0;
            #pragma unroll
            for (int kk = 0; kk < 8; ++kk) {
                accR[j] = fmaf(vcur[kk], wr[kk], accR[j]);
                accU[j] = fmaf(vcur[kk], wu[kk], accU[j]);
                accM[j] = fmaf(vcur[kk], wm[kk], accM[j]);
            }
        }
        #pragma unroll
        for (int kk = 0; kk < 8; ++kk) vcur[kk] = vnxt[kk];
    }

    #pragma unroll
    for (int j = 0; j < 8; ++j) {
        const int c = c0 + j;
        const float hr = accR[j] + bias[c];
        const float hu = accU[j] + bias[96 + c];
        const float hm = accM[j] + bias[192 + c];
        const float ir = i2h_t[((size_t)b * 288 + c) * HW_ + hw];
        const float iu = i2h_t[((size_t)b * 288 + 96 + c) * HW_ + hw];
        const float im = i2h_t[((size_t)b * 288 + 192 + c) * HW_ + hw];
        const float r  = sigmoid_f(ir + hr);
        const float u  = sigmoid_f(iu + hu);
        const float mem = leaky_f(im + r * hm);
        const float hv = h[((size_t)b * C_ + c) * HW_ + hw];
        const float hn = u * hv + (1.f - u) * mem;
        h_next[((size_t)b * C_ + c) * HW_ + hw] = hn;
        ys[((size_t)b * (T_ * C_) + (size_t)t * C_ + c) * HW_ + hw] = hn;
    }
}

// ---------------------------------------------------------------------------
// ConvTranspose2d k=4 s=2 p=1, 960 -> 960, 32x32 -> 64x64, + bias + leaky.
// ct_w layout (in,out,kh,kw). 2x2 output quad per input pixel, 8 oc/thread,
// ic unrolled by 2. block 256 = 32x8; grid (4, 120, B).
// ---------------------------------------------------------------------------
__global__ __launch_bounds__(256) void convtrans_k(
    const float* __restrict__ y, const float* __restrict__ w,
    const float* __restrict__ bias, float* __restrict__ out)
{
    const int tx  = threadIdx.x & 31;
    const int ty  = threadIdx.x >> 5;
    const int iy0 = blockIdx.x * 8;
    const int oc0 = blockIdx.y * 8;
    const int b   = blockIdx.z;
    const int NC  = T_ * C_;  // 960

    __shared__ float tile[2][10][34];
    float acc[8][2][2];
    #pragma unroll
    for (int j = 0; j < 8; ++j)
        #pragma unroll
        for (int ry = 0; ry < 2; ++ry)
            #pragma unroll
            for (int rx = 0; rx < 2; ++rx) acc[j][ry][rx] = 0.f;

    const float* yb = y + (size_t)b * NC * HW_;
    for (int ic = 0; ic < NC; ic += 2) {
        for (int i = threadIdx.x; i < 2 * 340; i += 256) {
            int ch = i / 340, rr = i - ch * 340;
            int r = rr / 34, cc = rr - r * 34;
            int yy = iy0 + r - 1, xx = cc - 1;
            tile[ch][r][cc] = (yy >= 0 && yy < 32 && xx >= 0 && xx < 32)
                              ? yb[(size_t)(ic + ch) * HW_ + yy * 32 + xx] : 0.f;
        }
        __syncthreads();
        #pragma unroll
        for (int ch = 0; ch < 2; ++ch) {
            float v[3][3];
            #pragma unroll
            for (int dy = 0; dy < 3; ++dy)
                #pragma unroll
                for (int dx = 0; dx < 3; ++dx)
                    v[dy][dx] = tile[ch][ty + dy][tx + dx];
            const float* wc = w + ((size_t)(ic + ch) * NC + oc0) * 16;
            #pragma unroll
            for (int j = 0; j < 8; ++j) {
                const float* wj = wc + (size_t)j * 16;
                #pragma unroll
                for (int ry = 0; ry < 2; ++ry)
                    #pragma unroll
                    for (int rx = 0; rx < 2; ++rx)
                        #pragma unroll
                        for (int a = 0; a < 2; ++a)
                            #pragma unroll
                            for (int e = 0; e < 2; ++e)
                                acc[j][ry][rx] = fmaf(v[a + ry][e + rx],
                                                      wj[(3 - 2*a - ry) * 4 + (3 - 2*e - rx)],
                                                      acc[j][ry][rx]);
            }
        }
        __syncthreads();
    }
    const int oyb = 2 * (iy0 + ty);
    #pragma unroll
    for (int j = 0; j < 8; ++j) {
        const float bs = bias[oc0 + j];
        #pragma unroll
        for (int ry = 0; ry < 2; ++ry) {
            float a0 = leaky_f(acc[j][ry][0] + bs);
            float a1 = leaky_f(acc[j][ry][1] + bs);
            float2 pr; pr.x = a0; pr.y = a1;
            *reinterpret_cast<float2*>(out + (((size_t)b * NC + oc0 + j) * 64 + oyb + ry) * 64 + 2 * tx) = pr;
        }
    }
}

// ---------------------------------------------------------------------------
extern "C" void kernel_launch(void* const* d_in, const int* in_sizes, int n_in,
                              void* d_out, int out_size, void* d_ws, size_t ws_size,
                              hipStream_t stream)
{
    const float* x      = (const float*)d_in[0];
    const float* h0     = (const float*)d_in[1];
    const float* i2h_w  = (const float*)d_in[2];
    const float* i2h_b  = (const float*)d_in[3];
    const float* i2f_w  = (const float*)d_in[4];
    const float* i2f_b  = (const float*)d_in[5];
    const float* h2f_w  = (const float*)d_in[6];
    const float* h2f_b  = (const float*)d_in[7];
    const float* flow_w = (const float*)d_in[8];
    const float* flow_b = (const float*)d_in[9];
    const float* ret_w  = (const float*)d_in[10];
    const float* ret_b  = (const float*)d_in[11];
    const float* ct_w   = (const float*)d_in[12];
    const float* ct_b   = (const float*)d_in[13];
    float* out = (float*)d_out;

    char* p = (char*)d_ws;
    float* i2h_all = (float*)p; p += (size_t)T_ * B_ * 288 * HW_ * 4;   // 47.2 MB (T,B,288,HW)
    float* i2f_all = (float*)p; p += (size_t)T_ * B_ * 32 * HW_ * 4;    //  5.2 MB (T,B,32,HW)
    float* f_buf   = (float*)p; p += (size_t)B_ * 32 * HW_ * 4;         //  0.5 MB
    float* flows   = (float*)p; p += (size_t)B_ * 26 * HW_ * 4;         //  0.4 MB
    float* warped  = (float*)p; p += (size_t)B_ * (L_ * C_) * HW_ * 4;  // 20.4 MB
    float* hA      = (float*)p; p += (size_t)B_ * C_ * HW_ * 4;         //  1.6 MB
    float* hB      = (float*)p; p += (size_t)B_ * C_ * HW_ * 4;         //  1.6 MB
    float* ys      = (float*)p; p += (size_t)B_ * (T_ * C_) * HW_ * 4;  // 15.7 MB

    // hoisted input-only convs, full (T*B) parallelism
    conv3x3_i2h_k<<<dim3(4, 36, T_ * B_), 256, 0, stream>>>(x, i2h_w, i2h_b, i2h_all);
    conv5x5_x_k<<<dim3(16, 4, T_ * B_), 256, 0, stream>>>(x, i2f_w, i2f_b, i2f_all);

    const float* h_cur = h0;
    float* hbuf[2] = {hA, hB};

    for (int t = 0; t < T_; ++t) {
        conv5x5_k<<<dim3(16, 4, B_), 256, 0, stream>>>(
            h_cur, C_, C_, 32, h2f_w, h2f_b,
            i2f_all + (size_t)t * B_ * 32 * HW_, 1, f_buf);
        conv5x5_k<<<dim3(16, 4, B_), 256, 0, stream>>>(
            f_buf, 32, 32, 2 * L_, flow_w, flow_b, nullptr, 0, flows);
        warp_k<<<dim3(16, L_, B_), 256, 0, stream>>>(h_cur, flows, warped);
        float* h_next = hbuf[t & 1];
        retgru_k<<<dim3(16, 12, B_), 64, 0, stream>>>(
            warped, ret_w, ret_b,
            i2h_all + (size_t)t * B_ * 288 * HW_, h_cur, h_next, ys, t);
        h_cur = h_next;
    }
    convtrans_k<<<dim3(4, 120, B_), 256, 0, stream>>>(ys, ct_w, ct_b, out);
}

// Round 4
// 6108.767 us; speedup vs baseline: 2.1061x; 1.5258x over previous
//
#include <hip/hip_runtime.h>
#include <math.h>
#include <stddef.h>

#define B_  4
#define T_  10
#define C_  96
#define H_  32
#define W_  32
#define HW_ 1024
#define L_  13
#define OUT_ 96

typedef __attribute__((ext_vector_type(4))) float f32x4;
typedef __attribute__((ext_vector_type(8))) short bf16x8;

__device__ __forceinline__ float leaky_f(float v) { return v >= 0.f ? v : 0.2f * v; }
__device__ __forceinline__ float sigmoid_f(float v) { return 1.f / (1.f + expf(-v)); }
__device__ __forceinline__ unsigned short f2bf(float f) {
    unsigned u = __float_as_uint(f);
    return (unsigned short)((u + 0x7FFFu + ((u >> 16) & 1u)) >> 16);  // RNE
}
__device__ __forceinline__ void gload_lds16(const void* g, void* l) {
    __builtin_amdgcn_global_load_lds(
        (const __attribute__((address_space(1))) unsigned int*)g,
        (__attribute__((address_space(3))) unsigned int*)l, 16, 0, 0);
}

// ---------------------------------------------------------------------------
// 3x3 conv, pad 1, Cin=96 -> Cout=288, ALL timesteps at once.
// ---------------------------------------------------------------------------
__global__ __launch_bounds__(256) void conv3x3_i2h_k(
    const float* __restrict__ x, const float* __restrict__ w,
    const float* __restrict__ bias, float* __restrict__ out)
{
    const int tx  = threadIdx.x & 31;
    const int ty  = threadIdx.x >> 5;
    const int y0  = blockIdx.x * 8;
    const int oc0 = blockIdx.y * 8;
    const int n   = blockIdx.z;          // t*B + b
    const int b   = n % B_;
    const int t   = n / B_;
    const float* xin = x + ((size_t)(b * T_ + t) * C_) * HW_;

    __shared__ float tile[10][34];
    float acc[8] = {0.f,0.f,0.f,0.f,0.f,0.f,0.f,0.f};

    for (int c = 0; c < C_; ++c) {
        const float* xc = xin + (size_t)c * HW_;
        for (int i = threadIdx.x; i < 10 * 34; i += 256) {
            int r = i / 34, cc = i - r * 34;
            int yy = y0 + r - 1, xx = cc - 1;
            tile[r][cc] = (yy >= 0 && yy < 32 && xx >= 0 && xx < 32) ? xc[yy * 32 + xx] : 0.f;
        }
        __syncthreads();
        float v[3][3];
        #pragma unroll
        for (int dy = 0; dy < 3; ++dy)
            #pragma unroll
            for (int dx = 0; dx < 3; ++dx)
                v[dy][dx] = tile[ty + dy][tx + dx];
        const float* wc = w + (size_t)(oc0 * C_ + c) * 9;
        #pragma unroll
        for (int j = 0; j < 8; ++j) {
            const float* wj = wc + (size_t)j * C_ * 9;
            #pragma unroll
            for (int dy = 0; dy < 3; ++dy)
                #pragma unroll
                for (int dx = 0; dx < 3; ++dx)
                    acc[j] = fmaf(v[dy][dx], wj[dy * 3 + dx], acc[j]);
        }
        __syncthreads();
    }
    const int hw = (y0 + ty) * 32 + tx;
    #pragma unroll
    for (int j = 0; j < 8; ++j)
        out[((size_t)n * 288 + oc0 + j) * HW_ + hw] = acc[j] + bias[oc0 + j];
}

// ---------------------------------------------------------------------------
// 5x5 conv, pad 2, hoisted over T: x (B,T,C,HW) -> out (T,B,32,HW).
// ---------------------------------------------------------------------------
__global__ __launch_bounds__(256) void conv5x5_x_k(
    const float* __restrict__ x, const float* __restrict__ w,
    const float* __restrict__ bias, float* __restrict__ out)
{
    const int px  = threadIdx.x & 63;
    const int g   = threadIdx.x >> 6;
    const int row = px >> 5, col = px & 31;
    const int y0  = blockIdx.x * 2;
    const int oc0 = blockIdx.y * 8 + g * 2;
    const int n   = blockIdx.z;
    const int b   = n % B_;
    const int t   = n / B_;
    const float* xin = x + ((size_t)(b * T_ + t) * C_) * HW_;

    __shared__ float tile[6][36];
    float acc0 = 0.f, acc1 = 0.f;

    for (int c = 0; c < C_; ++c) {
        const float* xc = xin + (size_t)c * HW_;
        if (threadIdx.x < 216) {
            int r = threadIdx.x / 36, cc = threadIdx.x % 36;
            int yy = y0 + r - 2, xx = cc - 2;
            tile[r][cc] = (yy >= 0 && yy < 32 && xx >= 0 && xx < 32) ? xc[yy * 32 + xx] : 0.f;
        }
        __syncthreads();
        const float* w0 = w + ((size_t)oc0 * C_ + c) * 25;
        const float* w1 = w0 + (size_t)C_ * 25;
        #pragma unroll
        for (int dy = 0; dy < 5; ++dy)
            #pragma unroll
            for (int dx = 0; dx < 5; ++dx) {
                float v = tile[row + dy][col + dx];
                acc0 = fmaf(v, w0[dy * 5 + dx], acc0);
                acc1 = fmaf(v, w1[dy * 5 + dx], acc1);
            }
        __syncthreads();
    }
    const int hw = (y0 + row) * 32 + col;
    out[((size_t)n * 32 + oc0) * HW_ + hw]     = acc0 + bias[oc0];
    out[((size_t)n * 32 + oc0 + 1) * HW_ + hw] = acc1 + bias[oc0 + 1];
}

// ---------------------------------------------------------------------------
// per-step generic 5x5 conv, pad 2.
// ---------------------------------------------------------------------------
__global__ __launch_bounds__(256) void conv5x5_k(
    const float* __restrict__ in, int in_bstr, int cin, int cout,
    const float* __restrict__ w, const float* __restrict__ bias,
    const float* __restrict__ addsrc, int do_leaky,
    float* __restrict__ out)
{
    const int px  = threadIdx.x & 63;
    const int g   = threadIdx.x >> 6;
    const int row = px >> 5, col = px & 31;
    const int y0  = blockIdx.x * 2;
    const int oc0 = blockIdx.y * 8 + g * 2;
    const int b   = blockIdx.z;
    const int ocw0 = min(oc0, cout - 1);
    const int ocw1 = min(oc0 + 1, cout - 1);

    __shared__ float tile[6][36];
    float acc0 = 0.f, acc1 = 0.f;

    for (int c = 0; c < cin; ++c) {
        const float* xc = in + ((size_t)b * in_bstr + c) * HW_;
        if (threadIdx.x < 216) {
            int r = threadIdx.x / 36, cc = threadIdx.x % 36;
            int yy = y0 + r - 2, xx = cc - 2;
            tile[r][cc] = (yy >= 0 && yy < 32 && xx >= 0 && xx < 32) ? xc[yy * 32 + xx] : 0.f;
        }
        __syncthreads();
        const float* w0 = w + ((size_t)ocw0 * cin + c) * 25;
        const float* w1 = w + ((size_t)ocw1 * cin + c) * 25;
        #pragma unroll
        for (int dy = 0; dy < 5; ++dy)
            #pragma unroll
            for (int dx = 0; dx < 5; ++dx) {
                float v = tile[row + dy][col + dx];
                acc0 = fmaf(v, w0[dy * 5 + dx], acc0);
                acc1 = fmaf(v, w1[dy * 5 + dx], acc1);
            }
        __syncthreads();
    }
    const int hw = (y0 + row) * 32 + col;
    if (oc0 < cout) {
        float r = acc0 + bias[oc0];
        if (addsrc) r += addsrc[((size_t)b * cout + oc0) * HW_ + hw];
        if (do_leaky) r = leaky_f(r);
        out[((size_t)b * cout + oc0) * HW_ + hw] = r;
    }
    if (oc0 + 1 < cout) {
        float r = acc1 + bias[oc0 + 1];
        if (addsrc) r += addsrc[((size_t)b * cout + oc0 + 1) * HW_ + hw];
        if (do_leaky) r = leaky_f(r);
        out[((size_t)b * cout + oc0 + 1) * HW_ + hw] = r;
    }
}

// ---------------------------------------------------------------------------
// bilinear warp
// ---------------------------------------------------------------------------
__global__ __launch_bounds__(256) void warp_k(
    const float* __restrict__ h, const float* __restrict__ flows,
    float* __restrict__ warped)
{
    const int hw = (blockIdx.x << 6) + (threadIdx.x & 63);
    const int cg = threadIdx.x >> 6;  // 0..3
    const int l  = blockIdx.y;
    const int b  = blockIdx.z;
    const int py = hw >> 5, px = hw & 31;

    const float fx = flows[((size_t)b * (2 * L_) + 2 * l) * HW_ + hw];
    const float fy = flows[((size_t)b * (2 * L_) + 2 * l + 1) * HW_ + hw];
    const float gx = (float)px - fx;
    const float gy = (float)py - fy;
    const float x0f = floorf(gx), y0f = floorf(gy);
    const float wx = gx - x0f, wy = gy - y0f;
    const int x0 = (int)x0f, y0 = (int)y0f;
    const int x1 = x0 + 1, y1 = y0 + 1;

    const bool vx0 = (x0 >= 0 && x0 <= 31), vx1 = (x1 >= 0 && x1 <= 31);
    const bool vy0 = (y0 >= 0 && y0 <= 31), vy1 = (y1 >= 0 && y1 <= 31);
    const int xc0 = min(max(x0, 0), 31), xc1 = min(max(x1, 0), 31);
    const int yc0 = min(max(y0, 0), 31), yc1 = min(max(y1, 0), 31);
    const int o00 = yc0 * 32 + xc0, o01 = yc0 * 32 + xc1;
    const int o10 = yc1 * 32 + xc0, o11 = yc1 * 32 + xc1;
    const float w00 = (vx0 && vy0) ? (1.f - wx) * (1.f - wy) : 0.f;
    const float w01 = (vx1 && vy0) ? wx * (1.f - wy) : 0.f;
    const float w10 = (vx0 && vy1) ? (1.f - wx) * wy : 0.f;
    const float w11 = (vx1 && vy1) ? wx * wy : 0.f;

    const float* hb = h + ((size_t)b * C_ + cg * 24) * HW_;
    float* ob = warped + (((size_t)b * L_ + l) * C_ + cg * 24) * HW_ + hw;
    for (int cc = 0; cc < 24; ++cc) {
        const float* hc = hb + (size_t)cc * HW_;
        ob[(size_t)cc * HW_] = hc[o00] * w00 + hc[o01] * w01 + hc[o10] * w10 + hc[o11] * w11;
    }
}

// ---------------------------------------------------------------------------
// fused ret(1x1 conv) + GRU
// ---------------------------------------------------------------------------
__global__ __launch_bounds__(64) void retgru_k(
    const float* __restrict__ warped, const float* __restrict__ w,
    const float* __restrict__ bias, const float* __restrict__ i2h_t,
    const float* __restrict__ h, float* __restrict__ h_next,
    float* __restrict__ ys, int t)
{
    const int tid  = threadIdx.x;           // 0..63
    const int hw   = (blockIdx.x << 6) + tid;
    const int c0   = blockIdx.y * 8;
    const int b    = blockIdx.z;
    const int K    = L_ * C_;               // 1248

    const float* wb = warped + (size_t)b * K * HW_ + hw;
    float accR[8] = {0,0,0,0,0,0,0,0};
    float accU[8] = {0,0,0,0,0,0,0,0};
    float accM[8] = {0,0,0,0,0,0,0,0};

    float vcur[8];
    #pragma unroll
    for (int kk = 0; kk < 8; ++kk) vcur[kk] = wb[(size_t)kk * HW_];

    for (int k0 = 0; k0 < K; k0 += 8) {
        float vnxt[8];
        if (k0 + 8 < K) {
            #pragma unroll
            for (int kk = 0; kk < 8; ++kk) vnxt[kk] = wb[(size_t)(k0 + 8 + kk) * HW_];
        } else {
            #pragma unroll
            for (int kk = 0; kk < 8; ++kk) vnxt[kk] = 0.f;
        }
        #pragma unroll
        for (int j = 0; j < 8; ++j) {
            const float* wr = w + (size_t)(c0 + j) * K + k0;
            const float* wu = w + (size_t)(96 + c0 + j) * K + k0;
            const float* wm = w + (size_t)(192 + c0 + j) * K + k0;
            #pragma unroll
            for (int kk = 0; kk < 8; ++kk) {
                accR[j] = fmaf(vcur[kk], wr[kk], accR[j]);
                accU[j] = fmaf(vcur[kk], wu[kk], accU[j]);
                accM[j] = fmaf(vcur[kk], wm[kk], accM[j]);
            }
        }
        #pragma unroll
        for (int kk = 0; kk < 8; ++kk) vcur[kk] = vnxt[kk];
    }

    #pragma unroll
    for (int j = 0; j < 8; ++j) {
        const int c = c0 + j;
        const float hr = accR[j] + bias[c];
        const float hu = accU[j] + bias[96 + c];
        const float hm = accM[j] + bias[192 + c];
        const float ir = i2h_t[((size_t)b * 288 + c) * HW_ + hw];
        const float iu = i2h_t[((size_t)b * 288 + 96 + c) * HW_ + hw];
        const float im = i2h_t[((size_t)b * 288 + 192 + c) * HW_ + hw];
        const float r  = sigmoid_f(ir + hr);
        const float u  = sigmoid_f(iu + hu);
        const float mem = leaky_f(im + r * hm);
        const float hv = h[((size_t)b * C_ + c) * HW_ + hw];
        const float hn = u * hv + (1.f - u) * mem;
        h_next[((size_t)b * C_ + c) * HW_ + hw] = hn;
        ys[((size_t)b * (T_ * C_) + (size_t)t * C_ + c) * HW_ + hw] = hn;
    }
}

// ---------------------------------------------------------------------------
// wprep: pack ConvT weights per parity into bf16 Wp[p][oc(1024 pad)][k=ic*4+a*2+e]
// Wp[p][oc][ic,a,e] = ct_w[ic][oc][3-2a-ry][3-2e-rx]; pad oc rows zeroed.
// ---------------------------------------------------------------------------
__global__ __launch_bounds__(256) void wprep_k(
    const float* __restrict__ ct_w, unsigned short* __restrict__ Wp)
{
    const int idx = blockIdx.x * 256 + threadIdx.x;   // 4*1024*960
    const int ic  = idx % 960;
    const int oc  = (idx / 960) & 1023;
    const int p   = idx / (960 * 1024);
    const int ry  = p >> 1, rx = p & 1;

    unsigned long long pack = 0ull;
    if (oc < 960) {
        #pragma unroll
        for (int a = 0; a < 2; ++a)
            #pragma unroll
            for (int e = 0; e < 2; ++e) {
                const int ky = 3 - 2 * a - ry, kx = 3 - 2 * e - rx;
                float f = ct_w[(((size_t)ic * 960 + oc) * 4 + ky) * 4 + kx];
                pack |= (unsigned long long)f2bf(f) << ((a * 2 + e) * 16);
            }
    }
    *(unsigned long long*)(Wp + ((size_t)(p * 1024 + oc) * 3840 + ic * 4)) = pack;
}

// ---------------------------------------------------------------------------
// qprep: shared im2col Q[pos=b*1156+Y*34+X][k=ic*4+dy*2+dx] (bf16)
//      = ys[b][ic][Y-1+dy][X-1+dx], 0 outside. Covers all 4 parities:
// parity (ry,rx) B-row for pixel (b,y,x) is pos=(b,y+ry,x+rx).
// ---------------------------------------------------------------------------
__global__ __launch_bounds__(256) void qprep_k(
    const float* __restrict__ ys, unsigned short* __restrict__ Q)
{
    const int pos = blockIdx.x;                       // 0..4623
    const int ic  = blockIdx.y * 256 + threadIdx.x;
    if (ic >= 960) return;
    const int b   = pos / 1156;
    const int rem = pos % 1156;
    const int Y   = rem / 34, X = rem % 34;
    const float* yc = ys + ((size_t)b * 960 + ic) * HW_;

    unsigned long long pack = 0ull;
    #pragma unroll
    for (int dy = 0; dy < 2; ++dy)
        #pragma unroll
        for (int dx = 0; dx < 2; ++dx) {
            const int yy = Y - 1 + dy, xx = X - 1 + dx;
            float f = (yy >= 0 && yy < 32 && xx >= 0 && xx < 32) ? yc[yy * 32 + xx] : 0.f;
            pack |= (unsigned long long)f2bf(f) << ((dy * 2 + dx) * 16);
        }
    *(unsigned long long*)(Q + ((size_t)pos * 3840 + ic * 4)) = pack;
}

// ---------------------------------------------------------------------------
// ConvT as bf16 MFMA GEMM, one parity per blockIdx.z.
// C[oc, n=(b,y,x)] = sum_K Wp[oc][K] * Q[pos(n,parity)][K]; +bias, leaky,
// scatter-store to out[b][oc][2y+ry][2x+rx].
// Tile 128x128, BK=64, 4 waves (2x2 of 64x64), 16x16x32 MFMA.
// LDS rows 128B, chunk-swizzle c^(row&7) applied to global src AND ds_read.
// ---------------------------------------------------------------------------
__global__ __launch_bounds__(256) void convt_gemm_k(
    const unsigned short* __restrict__ Wp, const unsigned short* __restrict__ Q,
    const float* __restrict__ bias, float* __restrict__ out)
{
    __shared__ unsigned short sA[8192];   // 128 rows x 64 k x 2B = 16 KB
    __shared__ unsigned short sB[8192];

    const int t    = threadIdx.x;
    const int lane = t & 63;
    const int wave = t >> 6;
    const int wr   = wave >> 1, wc = wave & 1;
    const int l15  = lane & 15, l4 = lane >> 4;

    const int px0 = blockIdx.x * 128;
    const int oc0 = blockIdx.y * 128;
    const int p   = blockIdx.z;
    const int ry  = p >> 1, rx = p & 1;
    const unsigned short* Wpp = Wp + (size_t)p * 1024 * 3840;

    // staging source pointers + LDS offsets (K-step invariant)
    const unsigned short* aPtr[4];
    const unsigned short* bPtr[4];
    int ldsOff[4];
    #pragma unroll
    for (int i = 0; i < 4; ++i) {
        const int lin = i * 256 + t;
        const int r   = lin >> 3;
        const int c   = (lin & 7) ^ (r & 7);   // inverse-swizzled source chunk
        aPtr[i] = Wpp + (size_t)(oc0 + r) * 3840 + c * 8;
        const int px = px0 + r;
        const int bb = px >> 10, yy = (px >> 5) & 31, xx = px & 31;
        const int qrow = bb * 1156 + (yy + ry) * 34 + (xx + rx);
        bPtr[i] = Q + (size_t)qrow * 3840 + c * 8;
        ldsOff[i] = lin * 8;                   // ushort units (16B chunks)
    }

    // fragment ds_read byte offsets (K-step invariant, swizzled)
    int offA[4][2], offB[4][2];
    #pragma unroll
    for (int m = 0; m < 4; ++m) {
        const int rA = wr * 64 + m * 16 + l15;
        const int rB = wc * 64 + m * 16 + l15;
        #pragma unroll
        for (int kk = 0; kk < 2; ++kk) {
            const int j = kk * 4 + l4;
            offA[m][kk] = rA * 128 + ((j ^ (rA & 7)) << 4);
            offB[m][kk] = rB * 128 + ((j ^ (rB & 7)) << 4);
        }
    }

    f32x4 acc[4][4];
    #pragma unroll
    for (int m = 0; m < 4; ++m)
        #pragma unroll
        for (int n = 0; n < 4; ++n)
            acc[m][n] = (f32x4){0.f, 0.f, 0.f, 0.f};

    const char* sAc = (const char*)sA;
    const char* sBc = (const char*)sB;

    for (int ks = 0; ks < 60; ++ks) {
        const int k0 = ks * 64;
        #pragma unroll
        for (int i = 0; i < 4; ++i) {
            gload_lds16(aPtr[i] + k0, (void*)(sA + ldsOff[i]));
            gload_lds16(bPtr[i] + k0, (void*)(sB + ldsOff[i]));
        }
        __syncthreads();
        #pragma unroll
        for (int kk = 0; kk < 2; ++kk) {
            bf16x8 av[4], bv[4];
            #pragma unroll
            for (int m = 0; m < 4; ++m) av[m] = *(const bf16x8*)(sAc + offA[m][kk]);
            #pragma unroll
            for (int n = 0; n < 4; ++n) bv[n] = *(const bf16x8*)(sBc + offB[n][kk]);
            #pragma unroll
            for (int m = 0; m < 4; ++m)
                #pragma unroll
                for (int n = 0; n < 4; ++n)
                    acc[m][n] = __builtin_amdgcn_mfma_f32_16x16x32_bf16(
                        av[m], bv[n], acc[m][n], 0, 0, 0);
        }
        __syncthreads();
    }

    // epilogue: C/D mapping col=lane&15, row=(lane>>4)*4+v
    #pragma unroll
    for (int m = 0; m < 4; ++m) {
        const int ocB = oc0 + wr * 64 + m * 16 + l4 * 4;
        #pragma unroll
        for (int n = 0; n < 4; ++n) {
            const int col = px0 + wc * 64 + n * 16 + l15;
            const int bb = col >> 10, yy = (col >> 5) & 31, xx = col & 31;
            #pragma unroll
            for (int v = 0; v < 4; ++v) {
                const int oc = ocB + v;
                if (oc < 960) {
                    const float val = leaky_f(acc[m][n][v] + bias[oc]);
                    out[(((size_t)bb * 960 + oc) * 64 + 2 * yy + ry) * 64 + 2 * xx + rx] = val;
                }
            }
        }
    }
}

// ---------------------------------------------------------------------------
extern "C" void kernel_launch(void* const* d_in, const int* in_sizes, int n_in,
                              void* d_out, int out_size, void* d_ws, size_t ws_size,
                              hipStream_t stream)
{
    const float* x      = (const float*)d_in[0];
    const float* h0     = (const float*)d_in[1];
    const float* i2h_w  = (const float*)d_in[2];
    const float* i2h_b  = (const float*)d_in[3];
    const float* i2f_w  = (const float*)d_in[4];
    const float* i2f_b  = (const float*)d_in[5];
    const float* h2f_w  = (const float*)d_in[6];
    const float* h2f_b  = (const float*)d_in[7];
    const float* flow_w = (const float*)d_in[8];
    const float* flow_b = (const float*)d_in[9];
    const float* ret_w  = (const float*)d_in[10];
    const float* ret_b  = (const float*)d_in[11];
    const float* ct_w   = (const float*)d_in[12];
    const float* ct_b   = (const float*)d_in[13];
    float* out = (float*)d_out;

    char* p = (char*)d_ws;
    float* i2h_all = (float*)p; p += (size_t)T_ * B_ * 288 * HW_ * 4;   // 47.2 MB
    float* i2f_all = (float*)p; p += (size_t)T_ * B_ * 32 * HW_ * 4;    //  5.2 MB
    float* f_buf   = (float*)p; p += (size_t)B_ * 32 * HW_ * 4;         //  0.5 MB
    float* flows   = (float*)p; p += (size_t)B_ * 26 * HW_ * 4;         //  0.4 MB
    float* warped  = (float*)p; p += (size_t)B_ * (L_ * C_) * HW_ * 4;  // 20.4 MB
    float* hA      = (float*)p; p += (size_t)B_ * C_ * HW_ * 4;         //  1.6 MB
    float* hB      = (float*)p; p += (size_t)B_ * C_ * HW_ * 4;         //  1.6 MB
    float* ys      = (float*)p; p += (size_t)B_ * (T_ * C_) * HW_ * 4;  // 15.7 MB

    // GEMM prep buffers ALIAS the loop-dead front region (i2h_all..warped):
    // Wp [0, 31457280), Q [31457280, 66969600) -- both < 76.9 MB dead span;
    // ys (live) starts at 76972032. Preps run AFTER the T-loop.
    unsigned short* Wp = (unsigned short*)d_ws;
    unsigned short* Q  = (unsigned short*)((char*)d_ws + (size_t)4 * 1024 * 3840 * 2);

    // hoisted input-only convs, full (T*B) parallelism
    conv3x3_i2h_k<<<dim3(4, 36, T_ * B_), 256, 0, stream>>>(x, i2h_w, i2h_b, i2h_all);
    conv5x5_x_k<<<dim3(16, 4, T_ * B_), 256, 0, stream>>>(x, i2f_w, i2f_b, i2f_all);

    const float* h_cur = h0;
    float* hbuf[2] = {hA, hB};

    for (int t = 0; t < T_; ++t) {
        conv5x5_k<<<dim3(16, 4, B_), 256, 0, stream>>>(
            h_cur, C_, C_, 32, h2f_w, h2f_b,
            i2f_all + (size_t)t * B_ * 32 * HW_, 1, f_buf);
        conv5x5_k<<<dim3(16, 4, B_), 256, 0, stream>>>(
            f_buf, 32, 32, 2 * L_, flow_w, flow_b, nullptr, 0, flows);
        warp_k<<<dim3(16, L_, B_), 256, 0, stream>>>(h_cur, flows, warped);
        float* h_next = hbuf[t & 1];
        retgru_k<<<dim3(16, 12, B_), 64, 0, stream>>>(
            warped, ret_w, ret_b,
            i2h_all + (size_t)t * B_ * 288 * HW_, h_cur, h_next, ys, t);
        h_cur = h_next;
    }

    // ConvTranspose: prep (weights + shared im2col) then 4-parity MFMA GEMM
    wprep_k<<<dim3((4 * 1024 * 960) / 256), 256, 0, stream>>>(ct_w, Wp);
    qprep_k<<<dim3(4624, 4), 256, 0, stream>>>(ys, Q);
    convt_gemm_k<<<dim3(32, 8, 4), 256, 0, stream>>>(Wp, Q, ct_b, out);
}

// Round 6
// 3813.214 us; speedup vs baseline: 3.3740x; 1.6020x over previous
//
#include <hip/hip_runtime.h>
#include <math.h>
#include <stddef.h>

#define B_  4
#define T_  10
#define C_  96
#define H_  32
#define W_  32
#define HW_ 1024
#define L_  13
#define OUT_ 96

typedef __attribute__((ext_vector_type(4))) float f32x4;
typedef __attribute__((ext_vector_type(8))) short bf16x8;

__device__ __forceinline__ float leaky_f(float v) { return v >= 0.f ? v : 0.2f * v; }
__device__ __forceinline__ float sigmoid_f(float v) { return 1.f / (1.f + expf(-v)); }
__device__ __forceinline__ unsigned short f2bf(float f) {
    unsigned u = __float_as_uint(f);
    return (unsigned short)((u + 0x7FFFu + ((u >> 16) & 1u)) >> 16);  // RNE
}
__device__ __forceinline__ float bf2f(unsigned short s) {
    return __uint_as_float((unsigned)s << 16);
}
__device__ __forceinline__ void gload_lds16(const void* g, void* l) {
    __builtin_amdgcn_global_load_lds(
        (const __attribute__((address_space(1))) unsigned int*)g,
        (__attribute__((address_space(3))) unsigned int*)l, 16, 0, 0);
}

// ---------------------------------------------------------------------------
// 5x5 conv, pad 2, hoisted over T: x (B,T,C,HW) -> out (T,B,32,HW).
// ---------------------------------------------------------------------------
__global__ __launch_bounds__(256) void conv5x5_x_k(
    const float* __restrict__ x, const float* __restrict__ w,
    const float* __restrict__ bias, float* __restrict__ out)
{
    const int px  = threadIdx.x & 63;
    const int g   = threadIdx.x >> 6;
    const int row = px >> 5, col = px & 31;
    const int y0  = blockIdx.x * 2;
    const int oc0 = blockIdx.y * 8 + g * 2;
    const int n   = blockIdx.z;
    const int b   = n % B_;
    const int t   = n / B_;
    const float* xin = x + ((size_t)(b * T_ + t) * C_) * HW_;

    __shared__ float tile[6][36];
    float acc0 = 0.f, acc1 = 0.f;

    for (int c = 0; c < C_; ++c) {
        const float* xc = xin + (size_t)c * HW_;
        if (threadIdx.x < 216) {
            int r = threadIdx.x / 36, cc = threadIdx.x % 36;
            int yy = y0 + r - 2, xx = cc - 2;
            tile[r][cc] = (yy >= 0 && yy < 32 && xx >= 0 && xx < 32) ? xc[yy * 32 + xx] : 0.f;
        }
        __syncthreads();
        const float* w0 = w + ((size_t)oc0 * C_ + c) * 25;
        const float* w1 = w0 + (size_t)C_ * 25;
        #pragma unroll
        for (int dy = 0; dy < 5; ++dy)
            #pragma unroll
            for (int dx = 0; dx < 5; ++dx) {
                float v = tile[row + dy][col + dx];
                acc0 = fmaf(v, w0[dy * 5 + dx], acc0);
                acc1 = fmaf(v, w1[dy * 5 + dx], acc1);
            }
        __syncthreads();
    }
    const int hw = (y0 + row) * 32 + col;
    out[((size_t)n * 32 + oc0) * HW_ + hw]     = acc0 + bias[oc0];
    out[((size_t)n * 32 + oc0 + 1) * HW_ + hw] = acc1 + bias[oc0 + 1];
}

// ---------------------------------------------------------------------------
// per-step generic 5x5 conv, pad 2.
// ---------------------------------------------------------------------------
__global__ __launch_bounds__(256) void conv5x5_k(
    const float* __restrict__ in, int in_bstr, int cin, int cout,
    const float* __restrict__ w, const float* __restrict__ bias,
    const float* __restrict__ addsrc, int do_leaky,
    float* __restrict__ out)
{
    const int px  = threadIdx.x & 63;
    const int g   = threadIdx.x >> 6;
    const int row = px >> 5, col = px & 31;
    const int y0  = blockIdx.x * 2;
    const int oc0 = blockIdx.y * 8 + g * 2;
    const int b   = blockIdx.z;
    const int ocw0 = min(oc0, cout - 1);
    const int ocw1 = min(oc0 + 1, cout - 1);

    __shared__ float tile[6][36];
    float acc0 = 0.f, acc1 = 0.f;

    for (int c = 0; c < cin; ++c) {
        const float* xc = in + ((size_t)b * in_bstr + c) * HW_;
        if (threadIdx.x < 216) {
            int r = threadIdx.x / 36, cc = threadIdx.x % 36;
            int yy = y0 + r - 2, xx = cc - 2;
            tile[r][cc] = (yy >= 0 && yy < 32 && xx >= 0 && xx < 32) ? xc[yy * 32 + xx] : 0.f;
        }
        __syncthreads();
        const float* w0 = w + ((size_t)ocw0 * cin + c) * 25;
        const float* w1 = w + ((size_t)ocw1 * cin + c) * 25;
        #pragma unroll
        for (int dy = 0; dy < 5; ++dy)
            #pragma unroll
            for (int dx = 0; dx < 5; ++dx) {
                float v = tile[row + dy][col + dx];
                acc0 = fmaf(v, w0[dy * 5 + dx], acc0);
                acc1 = fmaf(v, w1[dy * 5 + dx], acc1);
            }
        __syncthreads();
    }
    const int hw = (y0 + row) * 32 + col;
    if (oc0 < cout) {
        float r = acc0 + bias[oc0];
        if (addsrc) r += addsrc[((size_t)b * cout + oc0) * HW_ + hw];
        if (do_leaky) r = leaky_f(r);
        out[((size_t)b * cout + oc0) * HW_ + hw] = r;
    }
    if (oc0 + 1 < cout) {
        float r = acc1 + bias[oc0 + 1];
        if (addsrc) r += addsrc[((size_t)b * cout + oc0 + 1) * HW_ + hw];
        if (do_leaky) r = leaky_f(r);
        out[((size_t)b * cout + oc0 + 1) * HW_ + hw] = r;
    }
}

// ---------------------------------------------------------------------------
// bilinear warp -> SPLIT bf16 output: warped_s[b][2k+p][hw], k = l*C+c,
// p=0: hi = bf16(v), p=1: lo = bf16(v - hi).  (2496 channels per b)
// ---------------------------------------------------------------------------
__global__ __launch_bounds__(256) void warp_k(
    const float* __restrict__ h, const float* __restrict__ flows,
    unsigned short* __restrict__ warped_s)
{
    const int hw = (blockIdx.x << 6) + (threadIdx.x & 63);
    const int cg = threadIdx.x >> 6;  // 0..3
    const int l  = blockIdx.y;
    const int b  = blockIdx.z;
    const int py = hw >> 5, px = hw & 31;

    const float fx = flows[((size_t)b * (2 * L_) + 2 * l) * HW_ + hw];
    const float fy = flows[((size_t)b * (2 * L_) + 2 * l + 1) * HW_ + hw];
    const float gx = (float)px - fx;
    const float gy = (float)py - fy;
    const float x0f = floorf(gx), y0f = floorf(gy);
    const float wx = gx - x0f, wy = gy - y0f;
    const int x0 = (int)x0f, y0 = (int)y0f;
    const int x1 = x0 + 1, y1 = y0 + 1;

    const bool vx0 = (x0 >= 0 && x0 <= 31), vx1 = (x1 >= 0 && x1 <= 31);
    const bool vy0 = (y0 >= 0 && y0 <= 31), vy1 = (y1 >= 0 && y1 <= 31);
    const int xc0 = min(max(x0, 0), 31), xc1 = min(max(x1, 0), 31);
    const int yc0 = min(max(y0, 0), 31), yc1 = min(max(y1, 0), 31);
    const int o00 = yc0 * 32 + xc0, o01 = yc0 * 32 + xc1;
    const int o10 = yc1 * 32 + xc0, o11 = yc1 * 32 + xc1;
    const float w00 = (vx0 && vy0) ? (1.f - wx) * (1.f - wy) : 0.f;
    const float w01 = (vx1 && vy0) ? wx * (1.f - wy) : 0.f;
    const float w10 = (vx0 && vy1) ? (1.f - wx) * wy : 0.f;
    const float w11 = (vx1 && vy1) ? wx * wy : 0.f;

    const float* hb = h + ((size_t)b * C_ + cg * 24) * HW_;
    unsigned short* ob = warped_s + ((size_t)b * 2496 + 2 * (l * C_ + cg * 24)) * HW_ + hw;
    for (int cc = 0; cc < 24; ++cc) {
        const float* hc = hb + (size_t)cc * HW_;
        float v = hc[o00] * w00 + hc[o01] * w01 + hc[o10] * w10 + hc[o11] * w11;
        unsigned short hi = f2bf(v);
        ob[(size_t)(2 * cc) * HW_]     = hi;
        ob[(size_t)(2 * cc + 1) * HW_] = f2bf(v - bf2f(hi));
    }
}

// ---------------------------------------------------------------------------
// split weight preps.
// WxS[m(384)][k'(2624)]: k'<1728: whi(k=k'>>1); 1728<=k'<2592: wlo(k=k'-1728);
// else 0.  logical k = d*96+c (d=dy*3+dx), w = i2h_w[m][c][dy][dx].
// ---------------------------------------------------------------------------
__global__ __launch_bounds__(256) void wxprep_k(
    const float* __restrict__ i2h_w, unsigned short* __restrict__ WxS)
{
    const int idx = blockIdx.x * 256 + threadIdx.x;   // 384*2624
    const int m = idx / 2624, kp = idx - m * 2624;
    unsigned short r = 0;
    if (m < 288) {
        if (kp < 1728) {
            const int k = kp >> 1;
            const int d = k / 96, c = k - d * 96;
            r = f2bf(i2h_w[((size_t)m * 96 + c) * 9 + d]);
        } else if (kp < 2592) {
            const int k = kp - 1728;
            const int d = k / 96, c = k - d * 96;
            const float w = i2h_w[((size_t)m * 96 + c) * 9 + d];
            const unsigned short hi = f2bf(w);
            r = f2bf(w - bf2f(hi));
        }
    }
    WxS[idx] = r;
}

// WrS[m(384)][k'(3840)]: k'<2496: whi(k=k'>>1); 2496<=k'<3744: wlo(k=k'-2496)
__global__ __launch_bounds__(256) void wrprep_k(
    const float* __restrict__ ret_w, unsigned short* __restrict__ WrS)
{
    const int idx = blockIdx.x * 256 + threadIdx.x;   // 384*3840
    const int m = idx / 3840, kp = idx - m * 3840;
    unsigned short r = 0;
    if (m < 288) {
        if (kp < 2496) {
            r = f2bf(ret_w[(size_t)m * 1248 + (kp >> 1)]);
        } else if (kp < 3744) {
            const float w = ret_w[(size_t)m * 1248 + (kp - 2496)];
            const unsigned short hi = f2bf(w);
            r = f2bf(w - bf2f(hi));
        }
    }
    WrS[idx] = r;
}

// Wp[p][oc(1024)][k=ic*4+a*2+e] from ct_w (in,out,4,4)  (round-4 proven)
__global__ __launch_bounds__(256) void wprep_k(
    const float* __restrict__ ct_w, unsigned short* __restrict__ Wp)
{
    const int idx = blockIdx.x * 256 + threadIdx.x;   // 4*1024*960
    const int ic  = idx % 960;
    const int oc  = (idx / 960) & 1023;
    const int p   = idx / (960 * 1024);
    const int ry  = p >> 1, rx = p & 1;

    unsigned long long pack = 0ull;
    if (oc < 960) {
        #pragma unroll
        for (int a = 0; a < 2; ++a)
            #pragma unroll
            for (int e = 0; e < 2; ++e) {
                const int ky = 3 - 2 * a - ry, kx = 3 - 2 * e - rx;
                float f = ct_w[(((size_t)ic * 960 + oc) * 4 + ky) * 4 + kx];
                pack |= (unsigned long long)f2bf(f) << ((a * 2 + e) * 16);
            }
    }
    *(unsigned long long*)(Wp + ((size_t)(p * 1024 + oc) * 3840 + ic * 4)) = pack;
}

// ---------------------------------------------------------------------------
// i2h as split-bf16 MFMA GEMM with fused im2col staging. K'=2624 (41 steps).
// k'<1728: interleaved (vhi,vlo) pairs of k=k'>>1; 1728..2592: vhi... no:
// pairs region B'=(vhi,vlo), lo region B'=vhi?? -- see mapping:
//   sum = whi*(vhi+vlo) + wlo*vhi :  pairs A'=(whi,whi), lo-region A'=wlo B'=vhi
// Wait: lo region holds B'=vhi (A'=wlo). Output fp32 i2h_all (+bias).
// ---------------------------------------------------------------------------
__global__ __launch_bounds__(256) void i2h_gemm_k(
    const float* __restrict__ x, const unsigned short* __restrict__ WxS,
    const float* __restrict__ bias, float* __restrict__ out)
{
    __shared__ unsigned short sA[8192];   // 128 x 64k x 2B
    __shared__ unsigned short sB[8192];

    const int t    = threadIdx.x;
    const int lane = t & 63;
    const int wave = t >> 6;
    const int wr   = wave >> 1, wc = wave & 1;
    const int l15  = lane & 15, l4 = lane >> 4;

    const int px0 = blockIdx.x * 128;
    const int m0  = blockIdx.y * 128;

    const unsigned short* aPtr[4];
    int aOff[4];
    #pragma unroll
    for (int i = 0; i < 4; ++i) {
        const int lin = i * 256 + t;
        const int r = lin >> 3;
        const int c = (lin & 7) ^ (r & 7);
        aPtr[i] = WxS + (size_t)(m0 + r) * 2624 + c * 8;
        aOff[i] = lin * 8;
    }

    const int jr    = t & 127;
    const int cbase = t >> 7;                  // 0 or 1
    const int pos   = px0 + jr;
    const int img   = pos >> 10;               // t*B + b
    const int hw    = pos & 1023;
    const int ycell = hw >> 5, xcell = hw & 31;
    const int bb = img % B_, tt = img / B_;
    const float* xb = x + ((size_t)(bb * T_ + tt) * C_) * HW_;
    unsigned short* ldsB = sB + jr * 64;

    int offA[4][2], offB[4][2];
    #pragma unroll
    for (int m = 0; m < 4; ++m) {
        const int rA = wr * 64 + m * 16 + l15;
        const int rB = wc * 64 + m * 16 + l15;
        #pragma unroll
        for (int kk = 0; kk < 2; ++kk) {
            const int j = kk * 4 + l4;
            offA[m][kk] = rA * 128 + ((j ^ (rA & 7)) << 4);
            offB[m][kk] = rB * 128 + ((j ^ (rB & 7)) << 4);
        }
    }

    f32x4 acc[4][4];
    #pragma unroll
    for (int m = 0; m < 4; ++m)
        #pragma unroll
        for (int n = 0; n < 4; ++n)
            acc[m][n] = (f32x4){0.f, 0.f, 0.f, 0.f};

    const char* sAc = (const char*)sA;
    const char* sBc = (const char*)sB;

    for (int ks = 0; ks < 41; ++ks) {
        #pragma unroll
        for (int i = 0; i < 4; ++i)
            gload_lds16(aPtr[i] + ks * 64, (void*)(sA + aOff[i]));
        #pragma unroll
        for (int j = 0; j < 4; ++j) {
            const int cc = cbase + 2 * j;
            const int kc = ks * 8 + cc;
            bf16x8 pk = (bf16x8){0,0,0,0,0,0,0,0};
            if (kc < 216) {                       // (hi,lo) pairs, 4 k per chunk
                const int d  = kc / 24;
                const int c0 = (kc - d * 24) * 4;
                const int dy = d / 3, dx = d - dy * 3;
                const int yy = ycell - 1 + dy, xx = xcell - 1 + dx;
                const bool ok = (yy >= 0 && yy < 32 && xx >= 0 && xx < 32);
                const float* sp = xb + (size_t)c0 * HW_ + yy * 32 + xx;
                #pragma unroll
                for (int q = 0; q < 4; ++q) {
                    float v = ok ? sp[(size_t)q * HW_] : 0.f;
                    unsigned short hi = f2bf(v);
                    pk[2 * q]     = (short)hi;
                    pk[2 * q + 1] = (short)f2bf(v - bf2f(hi));
                }
            } else if (kc < 324) {                // hi-only region (pairs wlo)
                const int kL = kc - 216;
                const int d  = kL / 12;
                const int c0 = (kL - d * 12) * 8;
                const int dy = d / 3, dx = d - dy * 3;
                const int yy = ycell - 1 + dy, xx = xcell - 1 + dx;
                const bool ok = (yy >= 0 && yy < 32 && xx >= 0 && xx < 32);
                const float* sp = xb + (size_t)c0 * HW_ + yy * 32 + xx;
                #pragma unroll
                for (int q = 0; q < 8; ++q) {
                    float v = ok ? sp[(size_t)q * HW_] : 0.f;
                    pk[q] = (short)f2bf(v);
                }
            }
            *(bf16x8*)(ldsB + ((cc ^ (jr & 7)) << 3)) = pk;
        }
        __syncthreads();
        #pragma unroll
        for (int kk = 0; kk < 2; ++kk) {
            bf16x8 av[4], bv[4];
            #pragma unroll
            for (int m = 0; m < 4; ++m) av[m] = *(const bf16x8*)(sAc + offA[m][kk]);
            #pragma unroll
            for (int n = 0; n < 4; ++n) bv[n] = *(const bf16x8*)(sBc + offB[n][kk]);
            #pragma unroll
            for (int m = 0; m < 4; ++m)
                #pragma unroll
                for (int n = 0; n < 4; ++n)
                    acc[m][n] = __builtin_amdgcn_mfma_f32_16x16x32_bf16(
                        av[m], bv[n], acc[m][n], 0, 0, 0);
        }
        __syncthreads();
    }

    #pragma unroll
    for (int m = 0; m < 4; ++m) {
        const int mB = m0 + wr * 64 + m * 16 + l4 * 4;
        #pragma unroll
        for (int n = 0; n < 4; ++n) {
            const int col = px0 + wc * 64 + n * 16 + l15;
            const int oimg = col >> 10, ohw = col & 1023;
            #pragma unroll
            for (int v = 0; v < 4; ++v) {
                const int oc = mB + v;
                if (oc < 288)
                    out[((size_t)oimg * 288 + oc) * HW_ + ohw] = acc[m][n][v] + bias[oc];
            }
        }
    }
}

// ---------------------------------------------------------------------------
// ret 1x1 as split-bf16 MFMA GEMM. K'=3840 (60 steps).
// B chunks: kc<312: 8 consecutive split-channels (hi,lo interleaved storage);
// 312<=kc<468: vhi (even channels, stride 2); else 0. Out h2h fp32 (+bias).
// ---------------------------------------------------------------------------
__global__ __launch_bounds__(256) void ret_gemm_k(
    const unsigned short* __restrict__ warped_s, const unsigned short* __restrict__ WrS,
    const float* __restrict__ bias, float* __restrict__ h2h)
{
    __shared__ unsigned short sA[8192];
    __shared__ unsigned short sB[8192];

    const int t    = threadIdx.x;
    const int lane = t & 63;
    const int wave = t >> 6;
    const int wr   = wave >> 1, wc = wave & 1;
    const int l15  = lane & 15, l4 = lane >> 4;

    const int px0 = blockIdx.x * 128;
    const int m0  = blockIdx.y * 128;

    const unsigned short* aPtr[4];
    int aOff[4];
    #pragma unroll
    for (int i = 0; i < 4; ++i) {
        const int lin = i * 256 + t;
        const int r = lin >> 3;
        const int c = (lin & 7) ^ (r & 7);
        aPtr[i] = WrS + (size_t)(m0 + r) * 3840 + c * 8;
        aOff[i] = lin * 8;
    }

    const int jr    = t & 127;
    const int cbase = t >> 7;
    const int pos   = px0 + jr;
    const int bb    = pos >> 10;
    const int hw    = pos & 1023;
    const unsigned short* wbase = warped_s + (size_t)bb * 2496 * HW_ + hw;
    unsigned short* ldsB = sB + jr * 64;

    int offA[4][2], offB[4][2];
    #pragma unroll
    for (int m = 0; m < 4; ++m) {
        const int rA = wr * 64 + m * 16 + l15;
        const int rB = wc * 64 + m * 16 + l15;
        #pragma unroll
        for (int kk = 0; kk < 2; ++kk) {
            const int j = kk * 4 + l4;
            offA[m][kk] = rA * 128 + ((j ^ (rA & 7)) << 4);
            offB[m][kk] = rB * 128 + ((j ^ (rB & 7)) << 4);
        }
    }

    f32x4 acc[4][4];
    #pragma unroll
    for (int m = 0; m < 4; ++m)
        #pragma unroll
        for (int n = 0; n < 4; ++n)
            acc[m][n] = (f32x4){0.f, 0.f, 0.f, 0.f};

    const char* sAc = (const char*)sA;
    const char* sBc = (const char*)sB;

    for (int ks = 0; ks < 60; ++ks) {
        #pragma unroll
        for (int i = 0; i < 4; ++i)
            gload_lds16(aPtr[i] + ks * 64, (void*)(sA + aOff[i]));
        #pragma unroll
        for (int j = 0; j < 4; ++j) {
            const int cc = cbase + 2 * j;
            const int kc = ks * 8 + cc;
            bf16x8 pk = (bf16x8){0,0,0,0,0,0,0,0};
            if (kc < 312) {                       // interleaved (hi,lo) pairs
                const unsigned short* sp = wbase + (size_t)(kc * 8) * HW_;
                #pragma unroll
                for (int q = 0; q < 8; ++q)
                    pk[q] = (short)sp[(size_t)q * HW_];
            } else if (kc < 468) {                // vhi (even channels)
                const unsigned short* sp = wbase + (size_t)((kc - 312) * 16) * HW_;
                #pragma unroll
                for (int q = 0; q < 8; ++q)
                    pk[q] = (short)sp[(size_t)(2 * q) * HW_];
            }
            *(bf16x8*)(ldsB + ((cc ^ (jr & 7)) << 3)) = pk;
        }
        __syncthreads();
        #pragma unroll
        for (int kk = 0; kk < 2; ++kk) {
            bf16x8 av[4], bv[4];
            #pragma unroll
            for (int m = 0; m < 4; ++m) av[m] = *(const bf16x8*)(sAc + offA[m][kk]);
            #pragma unroll
            for (int n = 0; n < 4; ++n) bv[n] = *(const bf16x8*)(sBc + offB[n][kk]);
            #pragma unroll
            for (int m = 0; m < 4; ++m)
                #pragma unroll
                for (int n = 0; n < 4; ++n)
                    acc[m][n] = __builtin_amdgcn_mfma_f32_16x16x32_bf16(
                        av[m], bv[n], acc[m][n], 0, 0, 0);
        }
        __syncthreads();
    }

    #pragma unroll
    for (int m = 0; m < 4; ++m) {
        const int mB = m0 + wr * 64 + m * 16 + l4 * 4;
        #pragma unroll
        for (int n = 0; n < 4; ++n) {
            const int col = px0 + wc * 64 + n * 16 + l15;
            const int ob = col >> 10, ohw = col & 1023;
            #pragma unroll
            for (int v = 0; v < 4; ++v) {
                const int oc = mB + v;
                if (oc < 288)
                    h2h[((size_t)ob * 288 + oc) * HW_ + ohw] = acc[m][n][v] + bias[oc];
            }
        }
    }
}

// ---------------------------------------------------------------------------
// GRU gate update (bias already in both i2h_all and h2h). fp32 in, ysb bf16.
// ---------------------------------------------------------------------------
__global__ __launch_bounds__(256) void gru_k(
    const float* __restrict__ i2h_t, const float* __restrict__ h2h,
    const float* __restrict__ h, float* __restrict__ h_next,
    unsigned short* __restrict__ ysb, int t)
{
    const int idx = blockIdx.x * 256 + threadIdx.x;  // over B*C*HW
    const int hw = idx & (HW_ - 1);
    const int c  = (idx >> 10) % C_;
    const int b  = idx / (C_ * HW_);
    const size_t ibase = ((size_t)(t * B_ + b) * 288) * HW_ + hw;
    const size_t hbase = ((size_t)b * 288) * HW_ + hw;

    const float ir = i2h_t[ibase + (size_t)c * HW_];
    const float iu = i2h_t[ibase + (size_t)(96 + c) * HW_];
    const float im = i2h_t[ibase + (size_t)(192 + c) * HW_];
    const float hr = h2h[hbase + (size_t)c * HW_];
    const float hu = h2h[hbase + (size_t)(96 + c) * HW_];
    const float hm = h2h[hbase + (size_t)(192 + c) * HW_];

    const float r = sigmoid_f(ir + hr);
    const float u = sigmoid_f(iu + hu);
    const float mem = leaky_f(im + r * hm);
    const float hv = h[idx];
    const float hn = u * hv + (1.f - u) * mem;
    h_next[idx] = hn;
    ysb[((size_t)b * (T_ * C_) + (size_t)t * C_ + c) * HW_ + hw] = f2bf(hn);
}

// ---------------------------------------------------------------------------
// ConvT as bf16 MFMA GEMM, fused B-staging from ysb (bf16), parity=blockIdx.z.
// Tile 128x128, BK=64, K=3840 (60 steps), grid (32, 8, 4).
// ---------------------------------------------------------------------------
__global__ __launch_bounds__(256) void convt_gemm_k(
    const unsigned short* __restrict__ Wp, const unsigned short* __restrict__ ysb,
    const float* __restrict__ bias, float* __restrict__ out)
{
    __shared__ unsigned short sA[8192];
    __shared__ unsigned short sB[8192];

    const int t    = threadIdx.x;
    const int lane = t & 63;
    const int wave = t >> 6;
    const int wr   = wave >> 1, wc = wave & 1;
    const int l15  = lane & 15, l4 = lane >> 4;

    const int px0 = blockIdx.x * 128;
    const int oc0 = blockIdx.y * 128;
    const int p   = blockIdx.z;
    const int ry  = p >> 1, rx = p & 1;
    const unsigned short* Wpp = Wp + (size_t)p * 1024 * 3840;

    const unsigned short* aPtr[4];
    int aOff[4];
    #pragma unroll
    for (int i = 0; i < 4; ++i) {
        const int lin = i * 256 + t;
        const int r = lin >> 3;
        const int c = (lin & 7) ^ (r & 7);
        aPtr[i] = Wpp + (size_t)(oc0 + r) * 3840 + c * 8;
        aOff[i] = lin * 8;
    }

    const int jr    = t & 127;
    const int cbase = t >> 7;
    const int pos   = px0 + jr;
    const int bb    = pos >> 10;
    const int yy    = (pos >> 5) & 31, xx = pos & 31;
    const int Y = yy + ry, X = xx + rx;
    bool okt[4]; int offt[4];
    #pragma unroll
    for (int tp = 0; tp < 4; ++tp) {
        const int dy = tp >> 1, dx = tp & 1;
        const int sy = Y - 1 + dy, sx = X - 1 + dx;
        okt[tp] = (sy >= 0 && sy < 32 && sx >= 0 && sx < 32);
        offt[tp] = sy * 32 + sx;
    }
    const unsigned short* ybase = ysb + ((size_t)bb * 960) * HW_;
    unsigned short* ldsB = sB + jr * 64;

    int offA[4][2], offB[4][2];
    #pragma unroll
    for (int m = 0; m < 4; ++m) {
        const int rA = wr * 64 + m * 16 + l15;
        const int rB = wc * 64 + m * 16 + l15;
        #pragma unroll
        for (int kk = 0; kk < 2; ++kk) {
            const int j = kk * 4 + l4;
            offA[m][kk] = rA * 128 + ((j ^ (rA & 7)) << 4);
            offB[m][kk] = rB * 128 + ((j ^ (rB & 7)) << 4);
        }
    }

    f32x4 acc[4][4];
    #pragma unroll
    for (int m = 0; m < 4; ++m)
        #pragma unroll
        for (int n = 0; n < 4; ++n)
            acc[m][n] = (f32x4){0.f, 0.f, 0.f, 0.f};

    const char* sAc = (const char*)sA;
    const char* sBc = (const char*)sB;

    for (int ks = 0; ks < 60; ++ks) {
        #pragma unroll
        for (int i = 0; i < 4; ++i)
            gload_lds16(aPtr[i] + ks * 64, (void*)(sA + aOff[i]));
        #pragma unroll
        for (int j = 0; j < 4; ++j) {
            const int cc = cbase + 2 * j;
            const int ic0 = (ks * 8 + cc) * 2;
            bf16x8 pk;
            #pragma unroll
            for (int u = 0; u < 2; ++u) {
                const unsigned short* yc = ybase + (size_t)(ic0 + u) * HW_;
                #pragma unroll
                for (int tp = 0; tp < 4; ++tp)
                    pk[u * 4 + tp] = okt[tp] ? (short)yc[offt[tp]] : (short)0;
            }
            *(bf16x8*)(ldsB + ((cc ^ (jr & 7)) << 3)) = pk;
        }
        __syncthreads();
        #pragma unroll
        for (int kk = 0; kk < 2; ++kk) {
            bf16x8 av[4], bv[4];
            #pragma unroll
            for (int m = 0; m < 4; ++m) av[m] = *(const bf16x8*)(sAc + offA[m][kk]);
            #pragma unroll
            for (int n = 0; n < 4; ++n) bv[n] = *(const bf16x8*)(sBc + offB[n][kk]);
            #pragma unroll
            for (int m = 0; m < 4; ++m)
                #pragma unroll
                for (int n = 0; n < 4; ++n)
                    acc[m][n] = __builtin_amdgcn_mfma_f32_16x16x32_bf16(
                        av[m], bv[n], acc[m][n], 0, 0, 0);
        }
        __syncthreads();
    }

    #pragma unroll
    for (int m = 0; m < 4; ++m) {
        const int ocB = oc0 + wr * 64 + m * 16 + l4 * 4;
        #pragma unroll
        for (int n = 0; n < 4; ++n) {
            const int col = px0 + wc * 64 + n * 16 + l15;
            const int ob = col >> 10, oy = (col >> 5) & 31, ox = col & 31;
            #pragma unroll
            for (int v = 0; v < 4; ++v) {
                const int oc = ocB + v;
                if (oc < 960) {
                    const float val = leaky_f(acc[m][n][v] + bias[oc]);
                    out[(((size_t)ob * 960 + oc) * 64 + 2 * oy + ry) * 64 + 2 * ox + rx] = val;
                }
            }
        }
    }
}

// ---------------------------------------------------------------------------
extern "C" void kernel_launch(void* const* d_in, const int* in_sizes, int n_in,
                              void* d_out, int out_size, void* d_ws, size_t ws_size,
                              hipStream_t stream)
{
    const float* x      = (const float*)d_in[0];
    const float* h0     = (const float*)d_in[1];
    const float* i2h_w  = (const float*)d_in[2];
    const float* i2h_b  = (const float*)d_in[3];
    const float* i2f_w  = (const float*)d_in[4];
    const float* i2f_b  = (const float*)d_in[5];
    const float* h2f_w  = (const float*)d_in[6];
    const float* h2f_b  = (const float*)d_in[7];
    const float* flow_w = (const float*)d_in[8];
    const float* flow_b = (const float*)d_in[9];
    const float* ret_w  = (const float*)d_in[10];
    const float* ret_b  = (const float*)d_in[11];
    const float* ct_w   = (const float*)d_in[12];
    const float* ct_b   = (const float*)d_in[13];
    float* out = (float*)d_out;

    // workspace (94.5 MB total; round-4 proved >= 97.4 MB available)
    char* p = (char*)d_ws;
    float* i2h_all = (float*)p; p += (size_t)T_ * B_ * 288 * HW_ * 4;       // 47.19 MB fp32
    float* i2f_all = (float*)p; p += (size_t)T_ * B_ * 32 * HW_ * 4;        //  5.24 MB
    float* f_buf   = (float*)p; p += (size_t)B_ * 32 * HW_ * 4;             //  0.52 MB
    float* flows   = (float*)p; p += (size_t)B_ * 26 * HW_ * 4;             //  0.43 MB
    unsigned short* warped_s = (unsigned short*)p; p += (size_t)B_ * 2496 * HW_ * 2; // 20.45 MB split bf16
    float* h2h     = (float*)p; p += (size_t)B_ * 288 * HW_ * 4;            //  4.72 MB
    float* hA      = (float*)p; p += (size_t)B_ * C_ * HW_ * 4;             //  1.57 MB
    float* hB      = (float*)p; p += (size_t)B_ * C_ * HW_ * 4;             //  1.57 MB
    unsigned short* ysb = (unsigned short*)p; p += (size_t)B_ * (T_ * C_) * HW_ * 2; // 7.86 MB
    unsigned short* WxS = (unsigned short*)p; p += (size_t)384 * 2624 * 2;  //  2.02 MB
    unsigned short* WrS = (unsigned short*)p; p += (size_t)384 * 3840 * 2;  //  2.95 MB
    // Wp (31.46 MB) aliases i2h_all (dead after the T-loop), written post-loop
    unsigned short* Wp = (unsigned short*)d_ws;

    // weight packs + hoisted input convs
    wxprep_k<<<dim3((384 * 2624) / 256), 256, 0, stream>>>(i2h_w, WxS);
    wrprep_k<<<dim3((384 * 3840) / 256), 256, 0, stream>>>(ret_w, WrS);
    i2h_gemm_k<<<dim3(320, 3), 256, 0, stream>>>(x, WxS, i2h_b, i2h_all);
    conv5x5_x_k<<<dim3(16, 4, T_ * B_), 256, 0, stream>>>(x, i2f_w, i2f_b, i2f_all);

    const float* h_cur = h0;
    float* hbuf[2] = {hA, hB};

    for (int t = 0; t < T_; ++t) {
        conv5x5_k<<<dim3(16, 4, B_), 256, 0, stream>>>(
            h_cur, C_, C_, 32, h2f_w, h2f_b,
            i2f_all + (size_t)t * B_ * 32 * HW_, 1, f_buf);
        conv5x5_k<<<dim3(16, 4, B_), 256, 0, stream>>>(
            f_buf, 32, 32, 2 * L_, flow_w, flow_b, nullptr, 0, flows);
        warp_k<<<dim3(16, L_, B_), 256, 0, stream>>>(h_cur, flows, warped_s);
        ret_gemm_k<<<dim3(32, 3), 256, 0, stream>>>(warped_s, WrS, ret_b, h2h);
        float* h_next = hbuf[t & 1];
        gru_k<<<dim3((B_ * C_ * HW_) / 256), 256, 0, stream>>>(
            i2h_all, h2h, h_cur, h_next, ysb, t);
        h_cur = h_next;
    }

    wprep_k<<<dim3((4 * 1024 * 960) / 256), 256, 0, stream>>>(ct_w, Wp);
    convt_gemm_k<<<dim3(32, 8, 4), 256, 0, stream>>>(Wp, ysb, ct_b, out);
}

// Round 8
// 3722.453 us; speedup vs baseline: 3.4562x; 1.0244x over previous
//
#include <hip/hip_runtime.h>
#include <math.h>
#include <stddef.h>

#define B_  4
#define T_  10
#define C_  96
#define H_  32
#define W_  32
#define HW_ 1024
#define L_  13
#define OUT_ 96

typedef __attribute__((ext_vector_type(4))) float f32x4;
typedef __attribute__((ext_vector_type(8))) short bf16x8;

__device__ __forceinline__ float leaky_f(float v) { return v >= 0.f ? v : 0.2f * v; }
__device__ __forceinline__ float sigmoid_f(float v) { return 1.f / (1.f + expf(-v)); }
__device__ __forceinline__ unsigned short f2bf(float f) {
    unsigned u = __float_as_uint(f);
    return (unsigned short)((u + 0x7FFFu + ((u >> 16) & 1u)) >> 16);  // RNE
}
__device__ __forceinline__ float bf2f(unsigned short s) {
    return __uint_as_float((unsigned)s << 16);
}
__device__ __forceinline__ void gload_lds16(const void* g, void* l) {
    __builtin_amdgcn_global_load_lds(
        (const __attribute__((address_space(1))) unsigned int*)g,
        (__attribute__((address_space(3))) unsigned int*)l, 16, 0, 0);
}

// ---------------------------------------------------------------------------
// per-step generic 5x5 conv, pad 2. 4 channels staged per barrier (all 256
// threads), 200 FMA/barrier. block 256 = 64px x 4 oc-pairs; grid(16,cout/8,B)
// ---------------------------------------------------------------------------
__global__ __launch_bounds__(256) void conv5x5_k(
    const float* __restrict__ in, int in_bstr, int cin, int cout,
    const float* __restrict__ w, const float* __restrict__ bias,
    const float* __restrict__ addsrc, int do_leaky,
    float* __restrict__ out)
{
    const int px  = threadIdx.x & 63;
    const int g   = threadIdx.x >> 6;
    const int row = px >> 5, col = px & 31;
    const int y0  = blockIdx.x * 2;
    const int oc0 = blockIdx.y * 8 + g * 2;
    const int b   = blockIdx.z;
    const int ocw0 = min(oc0, cout - 1);
    const int ocw1 = min(oc0 + 1, cout - 1);

    __shared__ float tile[4][6][36];
    float acc0 = 0.f, acc1 = 0.f;

    for (int c0 = 0; c0 < cin; c0 += 4) {
        for (int i = threadIdx.x; i < 4 * 216; i += 256) {
            int ch = i / 216, rr = i - ch * 216;
            int r = rr / 36, cc = rr - r * 36;
            int yy = y0 + r - 2, xx = cc - 2;
            tile[ch][r][cc] = (yy >= 0 && yy < 32 && xx >= 0 && xx < 32)
                ? in[((size_t)b * in_bstr + c0 + ch) * HW_ + yy * 32 + xx] : 0.f;
        }
        __syncthreads();
        #pragma unroll
        for (int ch = 0; ch < 4; ++ch) {
            const float* w0 = w + ((size_t)ocw0 * cin + c0 + ch) * 25;
            const float* w1 = w + ((size_t)ocw1 * cin + c0 + ch) * 25;
            #pragma unroll
            for (int dy = 0; dy < 5; ++dy)
                #pragma unroll
                for (int dx = 0; dx < 5; ++dx) {
                    float v = tile[ch][row + dy][col + dx];
                    acc0 = fmaf(v, w0[dy * 5 + dx], acc0);
                    acc1 = fmaf(v, w1[dy * 5 + dx], acc1);
                }
        }
        __syncthreads();
    }
    const int hw = (y0 + row) * 32 + col;
    if (oc0 < cout) {
        float r = acc0 + bias[oc0];
        if (addsrc) r += addsrc[((size_t)b * cout + oc0) * HW_ + hw];
        if (do_leaky) r = leaky_f(r);
        out[((size_t)b * cout + oc0) * HW_ + hw] = r;
    }
    if (oc0 + 1 < cout) {
        float r = acc1 + bias[oc0 + 1];
        if (addsrc) r += addsrc[((size_t)b * cout + oc0 + 1) * HW_ + hw];
        if (do_leaky) r = leaky_f(r);
        out[((size_t)b * cout + oc0 + 1) * HW_ + hw] = r;
    }
}

// ---------------------------------------------------------------------------
// bilinear warp -> SPLIT bf16 output: warped_s[b][2k+p][hw], k = l*C+c,
// p=0: hi = bf16(v), p=1: lo = bf16(v - hi).  (2496 channels per b)
// ---------------------------------------------------------------------------
__global__ __launch_bounds__(256) void warp_k(
    const float* __restrict__ h, const float* __restrict__ flows,
    unsigned short* __restrict__ warped_s)
{
    const int hw = (blockIdx.x << 6) + (threadIdx.x & 63);
    const int cg = threadIdx.x >> 6;  // 0..3
    const int l  = blockIdx.y;
    const int b  = blockIdx.z;
    const int py = hw >> 5, px = hw & 31;

    const float fx = flows[((size_t)b * (2 * L_) + 2 * l) * HW_ + hw];
    const float fy = flows[((size_t)b * (2 * L_) + 2 * l + 1) * HW_ + hw];
    const float gx = (float)px - fx;
    const float gy = (float)py - fy;
    const float x0f = floorf(gx), y0f = floorf(gy);
    const float wx = gx - x0f, wy = gy - y0f;
    const int x0 = (int)x0f, y0 = (int)y0f;
    const int x1 = x0 + 1, y1 = y0 + 1;

    const bool vx0 = (x0 >= 0 && x0 <= 31), vx1 = (x1 >= 0 && x1 <= 31);
    const bool vy0 = (y0 >= 0 && y0 <= 31), vy1 = (y1 >= 0 && y1 <= 31);
    const int xc0 = min(max(x0, 0), 31), xc1 = min(max(x1, 0), 31);
    const int yc0 = min(max(y0, 0), 31), yc1 = min(max(y1, 0), 31);
    const int o00 = yc0 * 32 + xc0, o01 = yc0 * 32 + xc1;
    const int o10 = yc1 * 32 + xc0, o11 = yc1 * 32 + xc1;
    const float w00 = (vx0 && vy0) ? (1.f - wx) * (1.f - wy) : 0.f;
    const float w01 = (vx1 && vy0) ? wx * (1.f - wy) : 0.f;
    const float w10 = (vx0 && vy1) ? (1.f - wx) * wy : 0.f;
    const float w11 = (vx1 && vy1) ? wx * wy : 0.f;

    const float* hb = h + ((size_t)b * C_ + cg * 24) * HW_;
    unsigned short* ob = warped_s + ((size_t)b * 2496 + 2 * (l * C_ + cg * 24)) * HW_ + hw;
    for (int cc = 0; cc < 24; ++cc) {
        const float* hc = hb + (size_t)cc * HW_;
        float v = hc[o00] * w00 + hc[o01] * w01 + hc[o10] * w10 + hc[o11] * w11;
        unsigned short hi = f2bf(v);
        ob[(size_t)(2 * cc) * HW_]     = hi;
        ob[(size_t)(2 * cc + 1) * HW_] = f2bf(v - bf2f(hi));
    }
}

// ---------------------------------------------------------------------------
// split weight preps (hi region = pairs-expanded whi, then wlo region, pad 0)
// WxS[m(384)][k'(2624)]: k'<1728: whi(k=k'>>1); 1728..2592: wlo(k=k'-1728)
// logical k = d*96+c (d=dy*3+dx), w = i2h_w[m][c][dy][dx].
// ---------------------------------------------------------------------------
__global__ __launch_bounds__(256) void wxprep_k(
    const float* __restrict__ i2h_w, unsigned short* __restrict__ WxS)
{
    const int idx = blockIdx.x * 256 + threadIdx.x;   // 384*2624
    const int m = idx / 2624, kp = idx - m * 2624;
    unsigned short r = 0;
    if (m < 288) {
        if (kp < 1728) {
            const int k = kp >> 1;
            const int d = k / 96, c = k - d * 96;
            r = f2bf(i2h_w[((size_t)m * 96 + c) * 9 + d]);
        } else if (kp < 2592) {
            const int k = kp - 1728;
            const int d = k / 96, c = k - d * 96;
            const float w = i2h_w[((size_t)m * 96 + c) * 9 + d];
            const unsigned short hi = f2bf(w);
            r = f2bf(w - bf2f(hi));
        }
    }
    WxS[idx] = r;
}

// WrS[m(384)][k'(3840)]: k'<2496: whi(k=k'>>1); 2496..3744: wlo(k=k'-2496)
__global__ __launch_bounds__(256) void wrprep_k(
    const float* __restrict__ ret_w, unsigned short* __restrict__ WrS)
{
    const int idx = blockIdx.x * 256 + threadIdx.x;   // 384*3840
    const int m = idx / 3840, kp = idx - m * 3840;
    unsigned short r = 0;
    if (m < 288) {
        if (kp < 2496) {
            r = f2bf(ret_w[(size_t)m * 1248 + (kp >> 1)]);
        } else if (kp < 3744) {
            const float w = ret_w[(size_t)m * 1248 + (kp - 2496)];
            const unsigned short hi = f2bf(w);
            r = f2bf(w - bf2f(hi));
        }
    }
    WrS[idx] = r;
}

// WfS[oc(32)][k'(7232)]: k'<4800: whi(k=k'>>1); 4800..7200: wlo(k=k'-4800)
// logical k = d*96+c (d=dy*5+dx), w = i2f_w[oc][c][dy][dx].
__global__ __launch_bounds__(256) void wfprep_k(
    const float* __restrict__ i2f_w, unsigned short* __restrict__ WfS)
{
    const int idx = blockIdx.x * 256 + threadIdx.x;   // 32*7232
    const int oc = idx / 7232, kp = idx - oc * 7232;
    unsigned short r = 0;
    if (kp < 4800) {
        const int k = kp >> 1;
        const int d = k / 96, c = k - d * 96;
        r = f2bf(i2f_w[((size_t)oc * 96 + c) * 25 + d]);
    } else if (kp < 7200) {
        const int k = kp - 4800;
        const int d = k / 96, c = k - d * 96;
        const float w = i2f_w[((size_t)oc * 96 + c) * 25 + d];
        const unsigned short hi = f2bf(w);
        r = f2bf(w - bf2f(hi));
    }
    WfS[idx] = r;
}

// Wp[p][oc(1024)][k=ic*4+a*2+e] from ct_w (in,out,4,4)  (round-4 proven)
__global__ __launch_bounds__(256) void wprep_k(
    const float* __restrict__ ct_w, unsigned short* __restrict__ Wp)
{
    const int idx = blockIdx.x * 256 + threadIdx.x;   // 4*1024*960
    const int ic  = idx % 960;
    const int oc  = (idx / 960) & 1023;
    const int p   = idx / (960 * 1024);
    const int ry  = p >> 1, rx = p & 1;

    unsigned long long pack = 0ull;
    if (oc < 960) {
        #pragma unroll
        for (int a = 0; a < 2; ++a)
            #pragma unroll
            for (int e = 0; e < 2; ++e) {
                const int ky = 3 - 2 * a - ry, kx = 3 - 2 * e - rx;
                float f = ct_w[(((size_t)ic * 960 + oc) * 4 + ky) * 4 + kx];
                pack |= (unsigned long long)f2bf(f) << ((a * 2 + e) * 16);
            }
    }
    *(unsigned long long*)(Wp + ((size_t)(p * 1024 + oc) * 3840 + ic * 4)) = pack;
}

// ---------------------------------------------------------------------------
// i2f as split-bf16 MFMA GEMM with fused im2col staging (replaces VALU conv).
// C[oc(32)][pos(40960)] = sum_k' WfS[oc][k'] * B[pos][k'];  K'=7232 (113 steps)
// pairs region k'<4800: B=(vhi,vlo) of k=k'>>1; lo region: B=vhi(k=k'-4800).
// Tile 32x128, block 128 (2 waves of 32x64), grid 320. Out fp32 +bias.
// ---------------------------------------------------------------------------
__global__ __launch_bounds__(128) void i2f_gemm_k(
    const float* __restrict__ x, const unsigned short* __restrict__ WfS,
    const float* __restrict__ bias, float* __restrict__ out)
{
    __shared__ unsigned short sA[2048];   // 32 rows x 64 k
    __shared__ unsigned short sB[8192];   // 128 rows x 64 k

    const int t    = threadIdx.x;
    const int lane = t & 63;
    const int wave = t >> 6;              // 0..1 -> col offset wave*64
    const int l15  = lane & 15, l4 = lane >> 4;

    const int px0 = blockIdx.x * 128;

    // A staging: 256 chunks, 2 per thread (inverse-swizzled source)
    const unsigned short* aPtr[2];
    int aOff[2];
    #pragma unroll
    for (int i = 0; i < 2; ++i) {
        const int lin = i * 128 + t;
        const int r = lin >> 3;
        const int c = (lin & 7) ^ (r & 7);
        aPtr[i] = WfS + (size_t)r * 7232 + c * 8;
        aOff[i] = lin * 8;
    }

    // B im2col: thread t stages row t (pixel px0+t), 8 chunks per K-step
    const int jr  = t;
    const int pos = px0 + jr;
    const int img = pos >> 10;            // t*B + b
    const int hw  = pos & 1023;
    const int ycell = hw >> 5, xcell = hw & 31;
    const int bb = img % B_, tt = img / B_;
    const float* xb = x + ((size_t)(bb * T_ + tt) * C_) * HW_;
    unsigned short* ldsB = sB + jr * 64;

    int offA[2][2], offB[4][2];
    #pragma unroll
    for (int m = 0; m < 2; ++m) {
        const int rA = m * 16 + l15;
        #pragma unroll
        for (int kk = 0; kk < 2; ++kk) {
            const int j = kk * 4 + l4;
            offA[m][kk] = rA * 128 + ((j ^ (rA & 7)) << 4);
        }
    }
    #pragma unroll
    for (int n = 0; n < 4; ++n) {
        const int rB = wave * 64 + n * 16 + l15;
        #pragma unroll
        for (int kk = 0; kk < 2; ++kk) {
            const int j = kk * 4 + l4;
            offB[n][kk] = rB * 128 + ((j ^ (rB & 7)) << 4);
        }
    }

    f32x4 acc[2][4];
    #pragma unroll
    for (int m = 0; m < 2; ++m)
        #pragma unroll
        for (int n = 0; n < 4; ++n)
            acc[m][n] = (f32x4){0.f, 0.f, 0.f, 0.f};

    const char* sAc = (const char*)sA;
    const char* sBc = (const char*)sB;

    for (int ks = 0; ks < 113; ++ks) {
        #pragma unroll
        for (int i = 0; i < 2; ++i)
            gload_lds16(aPtr[i] + ks * 64, (void*)(sA + aOff[i]));
        #pragma unroll
        for (int cc = 0; cc < 8; ++cc) {
            const int kc = ks * 8 + cc;
            bf16x8 pk = (bf16x8){0,0,0,0,0,0,0,0};
            if (kc < 600) {                       // (hi,lo) pairs: 4 k per chunk
                const int k0 = kc * 4;
                const int d  = k0 / 96;
                const int c0 = k0 - d * 96;
                const int dy = d / 5, dx = d - dy * 5;
                const int yy = ycell - 2 + dy, xx = xcell - 2 + dx;
                const bool ok = (yy >= 0 && yy < 32 && xx >= 0 && xx < 32);
                const float* sp = xb + (size_t)c0 * HW_ + yy * 32 + xx;
                #pragma unroll
                for (int q = 0; q < 4; ++q) {
                    float v = ok ? sp[(size_t)q * HW_] : 0.f;
                    unsigned short hi = f2bf(v);
                    pk[2 * q]     = (short)hi;
                    pk[2 * q + 1] = (short)f2bf(v - bf2f(hi));
                }
            } else if (kc < 900) {                // vhi region (pairs wlo)
                const int kL = (kc - 600) * 8;
                const int d  = kL / 96;
                const int c0 = kL - d * 96;
                const int dy = d / 5, dx = d - dy * 5;
                const int yy = ycell - 2 + dy, xx = xcell - 2 + dx;
                const bool ok = (yy >= 0 && yy < 32 && xx >= 0 && xx < 32);
                const float* sp = xb + (size_t)c0 * HW_ + yy * 32 + xx;
                #pragma unroll
                for (int q = 0; q < 8; ++q) {
                    float v = ok ? sp[(size_t)q * HW_] : 0.f;
                    pk[q] = (short)f2bf(v);
                }
            }
            *(bf16x8*)(ldsB + ((cc ^ (jr & 7)) << 3)) = pk;
        }
        __syncthreads();
        #pragma unroll
        for (int kk = 0; kk < 2; ++kk) {
            bf16x8 av[2], bv[4];
            #pragma unroll
            for (int m = 0; m < 2; ++m) av[m] = *(const bf16x8*)(sAc + offA[m][kk]);
            #pragma unroll
            for (int n = 0; n < 4; ++n) bv[n] = *(const bf16x8*)(sBc + offB[n][kk]);
            #pragma unroll
            for (int m = 0; m < 2; ++m)
                #pragma unroll
                for (int n = 0; n < 4; ++n)
                    acc[m][n] = __builtin_amdgcn_mfma_f32_16x16x32_bf16(
                        av[m], bv[n], acc[m][n], 0, 0, 0);
        }
        __syncthreads();
    }

    #pragma unroll
    for (int m = 0; m < 2; ++m) {
        const int ocB = m * 16 + l4 * 4;
        #pragma unroll
        for (int n = 0; n < 4; ++n) {
            const int col = px0 + wave * 64 + n * 16 + l15;
            const int oimg = col >> 10, ohw = col & 1023;
            #pragma unroll
            for (int v = 0; v < 4; ++v) {
                const int oc = ocB + v;   // 0..31, all valid
                out[((size_t)oimg * 32 + oc) * HW_ + ohw] = acc[m][n][v] + bias[oc];
            }
        }
    }
}

// ---------------------------------------------------------------------------
// i2h as split-bf16 MFMA GEMM with fused im2col staging. K'=2624 (41 steps).
// pairs region kc<216: B=(vhi,vlo) of k=k'>>1; kc 216..324: B=vhi (vs wlo).
// Output fp32 i2h_all (+bias). Tile 128x128, grid (320, 3).  (round-6 proven)
// ---------------------------------------------------------------------------
__global__ __launch_bounds__(256) void i2h_gemm_k(
    const float* __restrict__ x, const unsigned short* __restrict__ WxS,
    const float* __restrict__ bias, float* __restrict__ out)
{
    __shared__ unsigned short sA[8192];   // 128 x 64k x 2B
    __shared__ unsigned short sB[8192];

    const int t    = threadIdx.x;
    const int lane = t & 63;
    const int wave = t >> 6;
    const int wr   = wave >> 1, wc = wave & 1;
    const int l15  = lane & 15, l4 = lane >> 4;

    const int px0 = blockIdx.x * 128;
    const int m0  = blockIdx.y * 128;

    const unsigned short* aPtr[4];
    int aOff[4];
    #pragma unroll
    for (int i = 0; i < 4; ++i) {
        const int lin = i * 256 + t;
        const int r = lin >> 3;
        const int c = (lin & 7) ^ (r & 7);
        aPtr[i] = WxS + (size_t)(m0 + r) * 2624 + c * 8;
        aOff[i] = lin * 8;
    }

    const int jr    = t & 127;
    const int cbase = t >> 7;                  // 0 or 1
    const int pos   = px0 + jr;
    const int img   = pos >> 10;               // t*B + b
    const int hw    = pos & 1023;
    const int ycell = hw >> 5, xcell = hw & 31;
    const int bb = img % B_, tt = img / B_;
    const float* xb = x + ((size_t)(bb * T_ + tt) * C_) * HW_;
    unsigned short* ldsB = sB + jr * 64;

    int offA[4][2], offB[4][2];
    #pragma unroll
    for (int m = 0; m < 4; ++m) {
        const int rA = wr * 64 + m * 16 + l15;
        const int rB = wc * 64 + m * 16 + l15;
        #pragma unroll
        for (int kk = 0; kk < 2; ++kk) {
            const int j = kk * 4 + l4;
            offA[m][kk] = rA * 128 + ((j ^ (rA & 7)) << 4);
            offB[m][kk] = rB * 128 + ((j ^ (rB & 7)) << 4);
        }
    }

    f32x4 acc[4][4];
    #pragma unroll
    for (int m = 0; m < 4; ++m)
        #pragma unroll
        for (int n = 0; n < 4; ++n)
            acc[m][n] = (f32x4){0.f, 0.f, 0.f, 0.f};

    const char* sAc = (const char*)sA;
    const char* sBc = (const char*)sB;

    for (int ks = 0; ks < 41; ++ks) {
        #pragma unroll
        for (int i = 0; i < 4; ++i)
            gload_lds16(aPtr[i] + ks * 64, (void*)(sA + aOff[i]));
        #pragma unroll
        for (int j = 0; j < 4; ++j) {
            const int cc = cbase + 2 * j;
            const int kc = ks * 8 + cc;
            bf16x8 pk = (bf16x8){0,0,0,0,0,0,0,0};
            if (kc < 216) {                       // (hi,lo) pairs, 4 k per chunk
                const int d  = kc / 24;
                const int c0 = (kc - d * 24) * 4;
                const int dy = d / 3, dx = d - dy * 3;
                const int yy = ycell - 1 + dy, xx = xcell - 1 + dx;
                const bool ok = (yy >= 0 && yy < 32 && xx >= 0 && xx < 32);
                const float* sp = xb + (size_t)c0 * HW_ + yy * 32 + xx;
                #pragma unroll
                for (int q = 0; q < 4; ++q) {
                    float v = ok ? sp[(size_t)q * HW_] : 0.f;
                    unsigned short hi = f2bf(v);
                    pk[2 * q]     = (short)hi;
                    pk[2 * q + 1] = (short)f2bf(v - bf2f(hi));
                }
            } else if (kc < 324) {                // vhi region (pairs wlo)
                const int kL = kc - 216;
                const int d  = kL / 12;
                const int c0 = (kL - d * 12) * 8;
                const int dy = d / 3, dx = d - dy * 3;
                const int yy = ycell - 1 + dy, xx = xcell - 1 + dx;
                const bool ok = (yy >= 0 && yy < 32 && xx >= 0 && xx < 32);
                const float* sp = xb + (size_t)c0 * HW_ + yy * 32 + xx;
                #pragma unroll
                for (int q = 0; q < 8; ++q) {
                    float v = ok ? sp[(size_t)q * HW_] : 0.f;
                    pk[q] = (short)f2bf(v);
                }
            }
            *(bf16x8*)(ldsB + ((cc ^ (jr & 7)) << 3)) = pk;
        }
        __syncthreads();
        #pragma unroll
        for (int kk = 0; kk < 2; ++kk) {
            bf16x8 av[4], bv[4];
            #pragma unroll
            for (int m = 0; m < 4; ++m) av[m] = *(const bf16x8*)(sAc + offA[m][kk]);
            #pragma unroll
            for (int n = 0; n < 4; ++n) bv[n] = *(const bf16x8*)(sBc + offB[n][kk]);
            #pragma unroll
            for (int m = 0; m < 4; ++m)
                #pragma unroll
                for (int n = 0; n < 4; ++n)
                    acc[m][n] = __builtin_amdgcn_mfma_f32_16x16x32_bf16(
                        av[m], bv[n], acc[m][n], 0, 0, 0);
        }
        __syncthreads();
    }

    #pragma unroll
    for (int m = 0; m < 4; ++m) {
        const int mB = m0 + wr * 64 + m * 16 + l4 * 4;
        #pragma unroll
        for (int n = 0; n < 4; ++n) {
            const int col = px0 + wc * 64 + n * 16 + l15;
            const int oimg = col >> 10, ohw = col & 1023;
            #pragma unroll
            for (int v = 0; v < 4; ++v) {
                const int oc = mB + v;
                if (oc < 288)
                    out[((size_t)oimg * 288 + oc) * HW_ + ohw] = acc[m][n][v] + bias[oc];
            }
        }
    }
}

// ---------------------------------------------------------------------------
// ret 1x1 as split-bf16 MFMA GEMM. K'=3840 (60 steps).  (round-6 proven)
// ---------------------------------------------------------------------------
__global__ __launch_bounds__(256) void ret_gemm_k(
    const unsigned short* __restrict__ warped_s, const unsigned short* __restrict__ WrS,
    const float* __restrict__ bias, float* __restrict__ h2h)
{
    __shared__ unsigned short sA[8192];
    __shared__ unsigned short sB[8192];

    const int t    = threadIdx.x;
    const int lane = t & 63;
    const int wave = t >> 6;
    const int wr   = wave >> 1, wc = wave & 1;
    const int l15  = lane & 15, l4 = lane >> 4;

    const int px0 = blockIdx.x * 128;
    const int m0  = blockIdx.y * 128;

    const unsigned short* aPtr[4];
    int aOff[4];
    #pragma unroll
    for (int i = 0; i < 4; ++i) {
        const int lin = i * 256 + t;
        const int r = lin >> 3;
        const int c = (lin & 7) ^ (r & 7);
        aPtr[i] = WrS + (size_t)(m0 + r) * 3840 + c * 8;
        aOff[i] = lin * 8;
    }

    const int jr    = t & 127;
    const int cbase = t >> 7;
    const int pos   = px0 + jr;
    const int bb    = pos >> 10;
    const int hw    = pos & 1023;
    const unsigned short* wbase = warped_s + (size_t)bb * 2496 * HW_ + hw;
    unsigned short* ldsB = sB + jr * 64;

    int offA[4][2], offB[4][2];
    #pragma unroll
    for (int m = 0; m < 4; ++m) {
        const int rA = wr * 64 + m * 16 + l15;
        const int rB = wc * 64 + m * 16 + l15;
        #pragma unroll
        for (int kk = 0; kk < 2; ++kk) {
            const int j = kk * 4 + l4;
            offA[m][kk] = rA * 128 + ((j ^ (rA & 7)) << 4);
            offB[m][kk] = rB * 128 + ((j ^ (rB & 7)) << 4);
        }
    }

    f32x4 acc[4][4];
    #pragma unroll
    for (int m = 0; m < 4; ++m)
        #pragma unroll
        for (int n = 0; n < 4; ++n)
            acc[m][n] = (f32x4){0.f, 0.f, 0.f, 0.f};

    const char* sAc = (const char*)sA;
    const char* sBc = (const char*)sB;

    for (int ks = 0; ks < 60; ++ks) {
        #pragma unroll
        for (int i = 0; i < 4; ++i)
            gload_lds16(aPtr[i] + ks * 64, (void*)(sA + aOff[i]));
        #pragma unroll
        for (int j = 0; j < 4; ++j) {
            const int cc = cbase + 2 * j;
            const int kc = ks * 8 + cc;
            bf16x8 pk = (bf16x8){0,0,0,0,0,0,0,0};
            if (kc < 312) {                       // interleaved (hi,lo) pairs
                const unsigned short* sp = wbase + (size_t)(kc * 8) * HW_;
                #pragma unroll
                for (int q = 0; q < 8; ++q)
                    pk[q] = (short)sp[(size_t)q * HW_];
            } else if (kc < 468) {                // vhi (even channels)
                const unsigned short* sp = wbase + (size_t)((kc - 312) * 16) * HW_;
                #pragma unroll
                for (int q = 0; q < 8; ++q)
                    pk[q] = (short)sp[(size_t)(2 * q) * HW_];
            }
            *(bf16x8*)(ldsB + ((cc ^ (jr & 7)) << 3)) = pk;
        }
        __syncthreads();
        #pragma unroll
        for (int kk = 0; kk < 2; ++kk) {
            bf16x8 av[4], bv[4];
            #pragma unroll
            for (int m = 0; m < 4; ++m) av[m] = *(const bf16x8*)(sAc + offA[m][kk]);
            #pragma unroll
            for (int n = 0; n < 4; ++n) bv[n] = *(const bf16x8*)(sBc + offB[n][kk]);
            #pragma unroll
            for (int m = 0; m < 4; ++m)
                #pragma unroll
                for (int n = 0; n < 4; ++n)
                    acc[m][n] = __builtin_amdgcn_mfma_f32_16x16x32_bf16(
                        av[m], bv[n], acc[m][n], 0, 0, 0);
        }
        __syncthreads();
    }

    #pragma unroll
    for (int m = 0; m < 4; ++m) {
        const int mB = m0 + wr * 64 + m * 16 + l4 * 4;
        #pragma unroll
        for (int n = 0; n < 4; ++n) {
            const int col = px0 + wc * 64 + n * 16 + l15;
            const int ob = col >> 10, ohw = col & 1023;
            #pragma unroll
            for (int v = 0; v < 4; ++v) {
                const int oc = mB + v;
                if (oc < 288)
                    h2h[((size_t)ob * 288 + oc) * HW_ + ohw] = acc[m][n][v] + bias[oc];
            }
        }
    }
}

// ---------------------------------------------------------------------------
// GRU gate update (bias already in both i2h_all and h2h). fp32 in, ysb bf16.
// ---------------------------------------------------------------------------
__global__ __launch_bounds__(256) void gru_k(
    const float* __restrict__ i2h_t, const float* __restrict__ h2h,
    const float* __restrict__ h, float* __restrict__ h_next,
    unsigned short* __restrict__ ysb, int t)
{
    const int idx = blockIdx.x * 256 + threadIdx.x;  // over B*C*HW
    const int hw = idx & (HW_ - 1);
    const int c  = (idx >> 10) % C_;
    const int b  = idx / (C_ * HW_);
    const size_t ibase = ((size_t)(t * B_ + b) * 288) * HW_ + hw;
    const size_t hbase = ((size_t)b * 288) * HW_ + hw;

    const float ir = i2h_t[ibase + (size_t)c * HW_];
    const float iu = i2h_t[ibase + (size_t)(96 + c) * HW_];
    const float im = i2h_t[ibase + (size_t)(192 + c) * HW_];
    const float hr = h2h[hbase + (size_t)c * HW_];
    const float hu = h2h[hbase + (size_t)(96 + c) * HW_];
    const float hm = h2h[hbase + (size_t)(192 + c) * HW_];

    const float r = sigmoid_f(ir + hr);
    const float u = sigmoid_f(iu + hu);
    const float mem = leaky_f(im + r * hm);
    const float hv = h[idx];
    const float hn = u * hv + (1.f - u) * mem;
    h_next[idx] = hn;
    ysb[((size_t)b * (T_ * C_) + (size_t)t * C_ + c) * HW_ + hw] = f2bf(hn);
}

// ---------------------------------------------------------------------------
// ConvT as bf16 MFMA GEMM, fused B-staging from ysb, parity=blockIdx.z.
// Tile 128x128, BK=64, K=3840 (60 steps), grid (32, 8, 4).  (round-6 proven)
// ---------------------------------------------------------------------------
__global__ __launch_bounds__(256) void convt_gemm_k(
    const unsigned short* __restrict__ Wp, const unsigned short* __restrict__ ysb,
    const float* __restrict__ bias, float* __restrict__ out)
{
    __shared__ unsigned short sA[8192];
    __shared__ unsigned short sB[8192];

    const int t    = threadIdx.x;
    const int lane = t & 63;
    const int wave = t >> 6;
    const int wr   = wave >> 1, wc = wave & 1;
    const int l15  = lane & 15, l4 = lane >> 4;

    const int px0 = blockIdx.x * 128;
    const int oc0 = blockIdx.y * 128;
    const int p   = blockIdx.z;
    const int ry  = p >> 1, rx = p & 1;
    const unsigned short* Wpp = Wp + (size_t)p * 1024 * 3840;

    const unsigned short* aPtr[4];
    int aOff[4];
    #pragma unroll
    for (int i = 0; i < 4; ++i) {
        const int lin = i * 256 + t;
        const int r = lin >> 3;
        const int c = (lin & 7) ^ (r & 7);
        aPtr[i] = Wpp + (size_t)(oc0 + r) * 3840 + c * 8;
        aOff[i] = lin * 8;
    }

    const int jr    = t & 127;
    const int cbase = t >> 7;
    const int pos   = px0 + jr;
    const int bb    = pos >> 10;
    const int yy    = (pos >> 5) & 31, xx = pos & 31;
    const int Y = yy + ry, X = xx + rx;
    bool okt[4]; int offt[4];
    #pragma unroll
    for (int tp = 0; tp < 4; ++tp) {
        const int dy = tp >> 1, dx = tp & 1;
        const int sy = Y - 1 + dy, sx = X - 1 + dx;
        okt[tp] = (sy >= 0 && sy < 32 && sx >= 0 && sx < 32);
        offt[tp] = sy * 32 + sx;
    }
    const unsigned short* ybase = ysb + ((size_t)bb * 960) * HW_;
    unsigned short* ldsB = sB + jr * 64;

    int offA[4][2], offB[4][2];
    #pragma unroll
    for (int m = 0; m < 4; ++m) {
        const int rA = wr * 64 + m * 16 + l15;
        const int rB = wc * 64 + m * 16 + l15;
        #pragma unroll
        for (int kk = 0; kk < 2; ++kk) {
            const int j = kk * 4 + l4;
            offA[m][kk] = rA * 128 + ((j ^ (rA & 7)) << 4);
            offB[m][kk] = rB * 128 + ((j ^ (rB & 7)) << 4);
        }
    }

    f32x4 acc[4][4];
    #pragma unroll
    for (int m = 0; m < 4; ++m)
        #pragma unroll
        for (int n = 0; n < 4; ++n)
            acc[m][n] = (f32x4){0.f, 0.f, 0.f, 0.f};

    const char* sAc = (const char*)sA;
    const char* sBc = (const char*)sB;

    for (int ks = 0; ks < 60; ++ks) {
        #pragma unroll
        for (int i = 0; i < 4; ++i)
            gload_lds16(aPtr[i] + ks * 64, (void*)(sA + aOff[i]));
        #pragma unroll
        for (int j = 0; j < 4; ++j) {
            const int cc = cbase + 2 * j;
            const int ic0 = (ks * 8 + cc) * 2;
            bf16x8 pk;
            #pragma unroll
            for (int u = 0; u < 2; ++u) {
                const unsigned short* yc = ybase + (size_t)(ic0 + u) * HW_;
                #pragma unroll
                for (int tp = 0; tp < 4; ++tp)
                    pk[u * 4 + tp] = okt[tp] ? (short)yc[offt[tp]] : (short)0;
            }
            *(bf16x8*)(ldsB + ((cc ^ (jr & 7)) << 3)) = pk;
        }
        __syncthreads();
        #pragma unroll
        for (int kk = 0; kk < 2; ++kk) {
            bf16x8 av[4], bv[4];
            #pragma unroll
            for (int m = 0; m < 4; ++m) av[m] = *(const bf16x8*)(sAc + offA[m][kk]);
            #pragma unroll
            for (int n = 0; n < 4; ++n) bv[n] = *(const bf16x8*)(sBc + offB[n][kk]);
            #pragma unroll
            for (int m = 0; m < 4; ++m)
                #pragma unroll
                for (int n = 0; n < 4; ++n)
                    acc[m][n] = __builtin_amdgcn_mfma_f32_16x16x32_bf16(
                        av[m], bv[n], acc[m][n], 0, 0, 0);
        }
        __syncthreads();
    }

    #pragma unroll
    for (int m = 0; m < 4; ++m) {
        const int ocB = oc0 + wr * 64 + m * 16 + l4 * 4;
        #pragma unroll
        for (int n = 0; n < 4; ++n) {
            const int col = px0 + wc * 64 + n * 16 + l15;
            const int ob = col >> 10, oy = (col >> 5) & 31, ox = col & 31;
            #pragma unroll
            for (int v = 0; v < 4; ++v) {
                const int oc = ocB + v;
                if (oc < 960) {
                    const float val = leaky_f(acc[m][n][v] + bias[oc]);
                    out[(((size_t)ob * 960 + oc) * 64 + 2 * oy + ry) * 64 + 2 * ox + rx] = val;
                }
            }
        }
    }
}

// ---------------------------------------------------------------------------
extern "C" void kernel_launch(void* const* d_in, const int* in_sizes, int n_in,
                              void* d_out, int out_size, void* d_ws, size_t ws_size,
                              hipStream_t stream)
{
    const float* x      = (const float*)d_in[0];
    const float* h0     = (const float*)d_in[1];
    const float* i2h_w  = (const float*)d_in[2];
    const float* i2h_b  = (const float*)d_in[3];
    const float* i2f_w  = (const float*)d_in[4];
    const float* i2f_b  = (const float*)d_in[5];
    const float* h2f_w  = (const float*)d_in[6];
    const float* h2f_b  = (const float*)d_in[7];
    const float* flow_w = (const float*)d_in[8];
    const float* flow_b = (const float*)d_in[9];
    const float* ret_w  = (const float*)d_in[10];
    const float* ret_b  = (const float*)d_in[11];
    const float* ct_w   = (const float*)d_in[12];
    const float* ct_b   = (const float*)d_in[13];
    float* out = (float*)d_out;

    // workspace (95.0 MB; 94.5 proven in r5/r6)
    char* p = (char*)d_ws;
    float* i2h_all = (float*)p; p += (size_t)T_ * B_ * 288 * HW_ * 4;       // 47.19 MB fp32
    float* i2f_all = (float*)p; p += (size_t)T_ * B_ * 32 * HW_ * 4;        //  5.24 MB
    float* f_buf   = (float*)p; p += (size_t)B_ * 32 * HW_ * 4;             //  0.52 MB
    float* flows   = (float*)p; p += (size_t)B_ * 26 * HW_ * 4;             //  0.43 MB
    unsigned short* warped_s = (unsigned short*)p; p += (size_t)B_ * 2496 * HW_ * 2; // 20.45 MB
    float* h2h     = (float*)p; p += (size_t)B_ * 288 * HW_ * 4;            //  4.72 MB
    float* hA      = (float*)p; p += (size_t)B_ * C_ * HW_ * 4;             //  1.57 MB
    float* hB      = (float*)p; p += (size_t)B_ * C_ * HW_ * 4;             //  1.57 MB
    unsigned short* ysb = (unsigned short*)p; p += (size_t)B_ * (T_ * C_) * HW_ * 2; // 7.86 MB
    unsigned short* WxS = (unsigned short*)p; p += (size_t)384 * 2624 * 2;  //  2.02 MB
    unsigned short* WrS = (unsigned short*)p; p += (size_t)384 * 3840 * 2;  //  2.95 MB
    unsigned short* WfS = (unsigned short*)p; p += (size_t)32 * 7232 * 2;   //  0.46 MB
    // Wp (31.46 MB) aliases i2h_all (dead after the T-loop), written post-loop
    unsigned short* Wp = (unsigned short*)d_ws;

    // weight packs + hoisted input GEMMs
    wxprep_k<<<dim3((384 * 2624) / 256), 256, 0, stream>>>(i2h_w, WxS);
    wrprep_k<<<dim3((384 * 3840) / 256), 256, 0, stream>>>(ret_w, WrS);
    wfprep_k<<<dim3((32 * 7232) / 256), 256, 0, stream>>>(i2f_w, WfS);
    i2h_gemm_k<<<dim3(320, 3), 256, 0, stream>>>(x, WxS, i2h_b, i2h_all);
    i2f_gemm_k<<<dim3(320), 128, 0, stream>>>(x, WfS, i2f_b, i2f_all);

    const float* h_cur = h0;
    float* hbuf[2] = {hA, hB};

    for (int t = 0; t < T_; ++t) {
        conv5x5_k<<<dim3(16, 4, B_), 256, 0, stream>>>(
            h_cur, C_, C_, 32, h2f_w, h2f_b,
            i2f_all + (size_t)t * B_ * 32 * HW_, 1, f_buf);
        conv5x5_k<<<dim3(16, 4, B_), 256, 0, stream>>>(
            f_buf, 32, 32, 2 * L_, flow_w, flow_b, nullptr, 0, flows);
        warp_k<<<dim3(16, L_, B_), 256, 0, stream>>>(h_cur, flows, warped_s);
        ret_gemm_k<<<dim3(32, 3), 256, 0, stream>>>(warped_s, WrS, ret_b, h2h);
        float* h_next = hbuf[t & 1];
        gru_k<<<dim3((B_ * C_ * HW_) / 256), 256, 0, stream>>>(
            i2h_all, h2h, h_cur, h_next, ysb, t);
        h_cur = h_next;
    }

    wprep_k<<<dim3((4 * 1024 * 960) / 256), 256, 0, stream>>>(ct_w, Wp);
    convt_gemm_k<<<dim3(32, 8, 4), 256, 0, stream>>>(Wp, ysb, ct_b, out);
}